// Round 14
// baseline (186.813 us; speedup 1.0000x reference)
//
#include <hip/hip_runtime.h>

typedef __bf16 bf16;
typedef __bf16 bf16x8 __attribute__((ext_vector_type(8)));
typedef __bf16 bf16x4 __attribute__((ext_vector_type(4)));
typedef float  f32x4  __attribute__((ext_vector_type(4)));
typedef float  f32x16 __attribute__((ext_vector_type(16)));
typedef unsigned u32x2 __attribute__((ext_vector_type(2)));
typedef unsigned u32x4 __attribute__((ext_vector_type(4)));
typedef unsigned long long uptr;

#define MFMA16(a, b, c) __builtin_amdgcn_mfma_f32_16x16x32_bf16((a), (b), (c), 0, 0, 0)
#define MFMA32(a, b, c) __builtin_amdgcn_mfma_f32_32x32x16_bf16((a), (b), (c), 0, 0, 0)

__device__ __forceinline__ void gl_lds16(const void* g, void* l) {
  __builtin_amdgcn_global_load_lds(
      (__attribute__((address_space(1))) void*)(uptr)(g),
      (__attribute__((address_space(3))) void*)(uptr)(l),
      16, 0, 0);
}
__device__ __forceinline__ void gl_lds4(const void* g, void* l) {
  __builtin_amdgcn_global_load_lds(
      (__attribute__((address_space(1))) void*)(uptr)(g),
      (__attribute__((address_space(3))) void*)(uptr)(l),
      4, 0, 0);
}
__device__ __forceinline__ unsigned cvtpk_bf16(float lo, float hi) {
  unsigned r;
  asm("v_cvt_pk_bf16_f32 %0, %1, %2" : "=v"(r) : "v"(lo), "v"(hi));
  return r;
}

// ---------------------------------------------------------------------------
// Fused prep. Wq/bq PRE-SCALED by 0.125*log2(e). Wma appended to Wqkvb
// (rows 3072..3327) and bma to bqkv. M2 = mask*(-1e9*log2e) - 40 (fixed shift).
__global__ __launch_bounds__(256) void fused_prep(
    const float* __restrict__ X, const float* __restrict__ Wq,
    const float* __restrict__ Wk, const float* __restrict__ Wv,
    const float* __restrict__ Wo, const float* __restrict__ Wma,
    const float* __restrict__ Wmp, const float* __restrict__ mask,
    const float* __restrict__ bq, const float* __restrict__ bk,
    const float* __restrict__ bv, const float* __restrict__ bma,
    const float* __restrict__ mv,
    bf16* __restrict__ Xb, bf16* __restrict__ Wqkvb, bf16* __restrict__ Wob,
    bf16* __restrict__ Wmpb,
    float* __restrict__ M2, float* __restrict__ bqkv, bf16* __restrict__ mvTb) {
  const int bid = blockIdx.x, t = threadIdx.x;
  const float QS = 0.125f * 1.44269504f;
  auto cvt = [&](const float* src, bf16* dst, int blk, float sc) {
    const long i = ((long)blk * 256 + t) * 4;
    const float4 v = *(const float4*)(src + i);
    bf16x4 o = {(bf16)(v.x * sc), (bf16)(v.y * sc), (bf16)(v.z * sc), (bf16)(v.w * sc)};
    *(bf16x4*)(dst + i) = o;
  };
  if (bid < 4096) cvt(X, Xb, bid, 1.0f);
  else if (bid < 5120) cvt(Wq, Wqkvb, bid - 4096, QS);
  else if (bid < 6144) cvt(Wk, Wqkvb + 1024 * 1024, bid - 5120, 1.0f);
  else if (bid < 7168) cvt(Wv, Wqkvb + 2 * 1024 * 1024, bid - 6144, 1.0f);
  else if (bid < 8192) cvt(Wo, Wob, bid - 7168, 1.0f);
  else if (bid < 8448) cvt(Wma, Wqkvb + 3072 * 1024, bid - 8192, 1.0f);
  else if (bid < 8960) cvt(Wmp, Wmpb, bid - 8448, 1.0f);
  else if (bid < 8964) {
    const long i = ((long)(bid - 8960) * 256 + t) * 4;
    const float4 v = *(const float4*)(mask + i);
    float4 o = {v.x * -1.44269504e9f - 40.0f, v.y * -1.44269504e9f - 40.0f,
                v.z * -1.44269504e9f - 40.0f, v.w * -1.44269504e9f - 40.0f};
    *(float4*)(M2 + i) = o;
  } else if (bid < 8967) {
    const int s = bid - 8964;
    const float* src = s == 0 ? bq : (s == 1 ? bk : bv);
    const float sc = s == 0 ? QS : 1.0f;
    float4 v = *(const float4*)(src + t * 4);
    float4 o = {v.x * sc, v.y * sc, v.z * sc, v.w * sc};
    *(float4*)(bqkv + s * 1024 + t * 4) = o;
  } else if (bid < 8968) {
    if (t < 64) *(float4*)(bqkv + 3072 + t * 4) = *(const float4*)(bma + t * 4);
  } else {
    const int d = bid - 8968;
    mvTb[(long)d * 256 + t] = (bf16)mv[(long)t * 512 + d];
  }
}

// row softmax over 256 cols, fp32 in, bf16 out. one wave per row.
__global__ __launch_bounds__(256) void softmax_rows256(const float* __restrict__ in,
                                                       bf16* __restrict__ out) {
  const int w = threadIdx.x >> 6, l = threadIdx.x & 63;
  const long row = (long)blockIdx.x * 4 + w;
  const float4 v = *(const float4*)(in + row * 256 + l * 4);
  float mx = fmaxf(fmaxf(v.x, v.y), fmaxf(v.z, v.w));
  mx = fmaxf(mx, __shfl_xor(mx, 1, 64));
  mx = fmaxf(mx, __shfl_xor(mx, 2, 64));
  mx = fmaxf(mx, __shfl_xor(mx, 4, 64));
  mx = fmaxf(mx, __shfl_xor(mx, 8, 64));
  mx = fmaxf(mx, __shfl_xor(mx, 16, 64));
  mx = fmaxf(mx, __shfl_xor(mx, 32, 64));
  const float e0 = __expf(v.x - mx), e1 = __expf(v.y - mx);
  const float e2 = __expf(v.z - mx), e3 = __expf(v.w - mx);
  float sm = e0 + e1 + e2 + e3;
  sm += __shfl_xor(sm, 1, 64);
  sm += __shfl_xor(sm, 2, 64);
  sm += __shfl_xor(sm, 4, 64);
  sm += __shfl_xor(sm, 8, 64);
  sm += __shfl_xor(sm, 16, 64);
  sm += __shfl_xor(sm, 32, 64);
  const float inv = 1.0f / sm;
  bf16x4 o = {(bf16)(e0 * inv), (bf16)(e1 * inv), (bf16)(e2 * inv), (bf16)(e3 * inv)};
  *(bf16x4*)(out + row * 256 + l * 4) = o;
}

// ---------------------------------------------------------------------------
// Generic GEMM: C[M][N] = (A[M][K] @ B[N][K]^T + bias)*alpha (+ combine-add)
template <typename OutT, bool COMBINE>
__global__ __launch_bounds__(256, 3) void gemm_bt(
    const bf16* __restrict__ A, const bf16* __restrict__ B,
    const float* __restrict__ bias, const bf16* __restrict__ Op,
    const float* __restrict__ mlp, OutT* __restrict__ C,
    int M, int N, int K, float alpha) {
  __shared__ bf16 lA[2][128 * 64];
  __shared__ bf16 lB[2][64 * 64];
  const int tid = threadIdx.x;
  const int w = tid >> 6, l = tid & 63;
  const int hi = l >> 4, lo = l & 15;
  const int m0 = blockIdx.y * 128, n0 = blockIdx.x * 64;
  const int wm = w * 32;

  const int sr8 = l >> 3;
  const int sc = (l & 7) * 8;
  const long aRow = (long)(m0 + wm + sr8);
  const long bRow = (long)(n0 + w * 16 + sr8);

  auto stage = [&](int p, int k0) {
#pragma unroll
    for (int j = 0; j < 4; ++j)
      gl_lds16(A + (aRow + 8 * j) * K + k0 + sc, (char*)lA[p] + (wm + 8 * j) * 128);
#pragma unroll
    for (int j = 0; j < 2; ++j)
      gl_lds16(B + (bRow + 8 * j) * K + k0 + sc, (char*)lB[p] + (w * 16 + 8 * j) * 128);
  };

  f32x4 acc[2][4] = {};
  stage(0, 0);
  __syncthreads();
  const int nt = K >> 6;

  for (int t = 0; t < nt; ++t) {
    const int p = t & 1;
    if (t + 1 < nt) stage(p ^ 1, (t + 1) << 6);
#pragma unroll
    for (int kk = 0; kk < 2; ++kk) {
      bf16x8 af[2], bfr[4];
#pragma unroll
      for (int mi = 0; mi < 2; ++mi)
        af[mi] = *(const bf16x8*)((const char*)lA[p] + (wm + mi * 16 + lo) * 128 + kk * 64 + hi * 16);
#pragma unroll
      for (int ni = 0; ni < 4; ++ni)
        bfr[ni] = *(const bf16x8*)((const char*)lB[p] + (ni * 16 + lo) * 128 + kk * 64 + hi * 16);
      __builtin_amdgcn_s_setprio(1);
#pragma unroll
      for (int mi = 0; mi < 2; ++mi)
#pragma unroll
        for (int ni = 0; ni < 4; ++ni)
          acc[mi][ni] = MFMA16(af[mi], bfr[ni], acc[mi][ni]);
      __builtin_amdgcn_s_setprio(0);
    }
    __syncthreads();
  }

#pragma unroll
  for (int ni = 0; ni < 4; ++ni) {
    const int col = n0 + ni * 16 + lo;
    const float bv = bias ? bias[col] : 0.0f;
#pragma unroll
    for (int mi = 0; mi < 2; ++mi) {
      const int mrow = m0 + wm + mi * 16 + hi * 4;
#pragma unroll
      for (int r = 0; r < 4; ++r) {
        const long row = mrow + r;
        float v = (acc[mi][ni][r] + bv) * alpha;
        if (COMBINE) {
          const int h = col >> 6;
          const float l0 = mlp[row * 16 + h];
          const float l1 = mlp[(4096L + row) * 16 + h];
          const float o0v = (float)Op[row * 1024 + col];
          const float o1v = (float)Op[4096L * 1024 + row * 1024 + col];
          v += (o0v + o1v) / (l0 + l1);
        }
        C[row * (long)N + col] = (OutT)v;
      }
    }
  }
}

// Fused QKV + mem-score projection, m97 128x128 structure, 4 blocks/CU,
// XCD-swizzled flat grid (832 = 8 XCD x 104; consecutive roles share B-panel).
__global__ __launch_bounds__(256, 4) void gemm_qkv(
    const bf16* __restrict__ A, const bf16* __restrict__ B,
    const float* __restrict__ bias, bf16* __restrict__ Qo,
    bf16* __restrict__ Ko, bf16* __restrict__ Vto, float* __restrict__ MSc) {
  const int K = 1024;
  __shared__ bf16 smem[2][128 * 64];   // lA | lB; reused as transpose buf
  bf16* lA = smem[0];
  bf16* lB = smem[1];
  const int lin = blockIdx.x;
  const int role = (lin & 7) * 104 + (lin >> 3);   // 832/8 = 104 per XCD
  const int m0 = (role & 31) * 128;                // m fastest within XCD
  const int n0 = (role >> 5) * 128;
  const int tid = threadIdx.x;
  const int w = tid >> 6, l = tid & 63;
  const int hi = l >> 4, lo = l & 15;
  const int wm = (w >> 1) * 64, wn = (w & 1) * 64;

  const int sr = w * 32 + (l >> 3);
  const int sc = (l & 7) * 8;
  const long aBase = (long)(m0 + sr) * K + sc;
  const long bBase = (long)(n0 + sr) * K + sc;

  f32x4 acc[4][4] = {};

  for (int k0 = 0; k0 < K; k0 += 64) {
#pragma unroll
    for (int j = 0; j < 4; ++j) {
      gl_lds16(A + aBase + (long)8 * j * K + k0, (char*)lA + (w * 32 + 8 * j) * 128);
      gl_lds16(B + bBase + (long)8 * j * K + k0, (char*)lB + (w * 32 + 8 * j) * 128);
    }
    __syncthreads();
#pragma unroll
    for (int kk = 0; kk < 2; ++kk) {
      bf16x8 af[4], bfr[4];
#pragma unroll
      for (int i = 0; i < 4; ++i) {
        af[i]  = *(const bf16x8*)((const char*)lA + (wm + i * 16 + lo) * 128 + kk * 64 + hi * 16);
        bfr[i] = *(const bf16x8*)((const char*)lB + (wn + i * 16 + lo) * 128 + kk * 64 + hi * 16);
      }
#pragma unroll
      for (int mi = 0; mi < 4; ++mi)
#pragma unroll
        for (int ni = 0; ni < 4; ++ni)
          acc[mi][ni] = MFMA16(af[mi], bfr[ni], acc[mi][ni]);
    }
    __syncthreads();
  }

  if (n0 < 2048) {       // Q or K
#pragma unroll
    for (int ni = 0; ni < 4; ++ni) {
      const int col = n0 + wn + ni * 16 + lo;
      const float bv = bias[col];
#pragma unroll
      for (int mi = 0; mi < 4; ++mi) {
        const int mrow = m0 + wm + mi * 16 + hi * 4;
#pragma unroll
        for (int r = 0; r < 4; ++r) {
          const long row = mrow + r;
          const float v = acc[mi][ni][r] + bv;
          if (n0 < 1024) Qo[row * 1024 + col] = (bf16)v;
          else           Ko[row * 1024 + (col - 1024)] = (bf16)v;
        }
      }
    }
  } else if (n0 < 3072) {  // V: transpose through LDS, coalesced Vt writes
    bf16* sT = smem[0];
#pragma unroll
    for (int ni = 0; ni < 4; ++ni) {
      const int cT = wn + ni * 16 + lo;
      const float bv = bias[n0 + cT];
#pragma unroll
      for (int mi = 0; mi < 4; ++mi) {
        const int rT = wm + mi * 16 + hi * 4;
        u32x2 pw = {cvtpk_bf16(acc[mi][ni][0] + bv, acc[mi][ni][1] + bv),
                    cvtpk_bf16(acc[mi][ni][2] + bv, acc[mi][ni][3] + bv)};
        *(u32x2*)((char*)sT + cT * 256 + ((rT * 2) ^ ((cT & 15) << 3))) = pw;
      }
    }
    __syncthreads();
    const long vrow0 = (long)(m0 >> 11) * 1024 + (n0 - 2048);
    const int srow = m0 & 2047;
#pragma unroll
    for (int dd = 0; dd < 32; ++dd) {
      const int d = w * 32 + dd;
      const unsigned pv = *(const unsigned*)((const char*)sT + d * 256 + ((l * 4) ^ ((d & 15) << 3)));
      *(unsigned*)((char*)(Vto + (vrow0 + d) * 2048 + srow) + l * 4) = pv;
    }
  } else {               // mem-scores -> MSc fp32 [4096][256]
#pragma unroll
    for (int ni = 0; ni < 4; ++ni) {
      const int col = n0 + wn + ni * 16 + lo;
      const float bv = bias[col];
      const int cm = col - 3072;
#pragma unroll
      for (int mi = 0; mi < 4; ++mi) {
        const int mrow = m0 + wm + mi * 16 + hi * 4;
#pragma unroll
        for (int r = 0; r < 4; ++r)
          MSc[(long)(mrow + r) * 256 + cm] = acc[mi][ni][r] + bv;
      }
    }
  }
}

// ---------------------------------------------------------------------------
// Flash attention, swapped-QK^T 32x32, KEY-SPLIT x2, FIXED-SHIFT softmax.
// Row-sum l computed ON THE MFMA PIPE: lsum = MFMA32(pa, oneB, lsum) where
// oneB = ones in B-column n=0 -> D[q][0] = sum_k P[q][k]. Replaces the
// 31-op VALU tree + cross-half shuffle per tile (R13 PMC: VALU 40% dominant).
__global__ __launch_bounds__(256, 4) void attn_fwd(
    const bf16* __restrict__ Q, const bf16* __restrict__ Km,
    const bf16* __restrict__ Vt, const float* __restrict__ M2,
    bf16* __restrict__ Opart, float* __restrict__ ml) {
  __shared__ bf16 lK[2][64 * 64];
  __shared__ bf16 lV[2][64 * 64];
  __shared__ alignas(16) float lM[2][64];
  const int tid = threadIdx.x, w = tid >> 6, l = tid & 63;
  const int q31 = l & 31, h32 = l >> 5;
  const int b = blockIdx.z >> 1, half = blockIdx.z & 1;
  const int hh = blockIdx.y, q0 = blockIdx.x * 128;
  const long S = 2048, H = 1024;
  const int kbase = half * 1024;

  bf16x8 qf[4];
  const long qrow = (long)b * S + q0 + w * 32 + q31;
#pragma unroll
  for (int sl = 0; sl < 4; ++sl)
    qf[sl] = *(const bf16x8*)(Q + qrow * H + hh * 64 + sl * 16 + h32 * 8);

  // ones-column B-frag: B[k][n] with n=lane&31, k=(lane>>5)*8+j.
  // n==0 lanes carry 1.0 in all 8 k-slots -> D[q][0] = row sum of A.
  bf16x8 oneB = {};
  if (q31 == 0) {
#pragma unroll
    for (int j = 0; j < 8; ++j) oneB[j] = (bf16)1.0f;
  }

  f32x16 o0 = {}, o1 = {}, lsum = {};

  const int swr = w * 16 + (l >> 3);
  const int swc = ((l & 7) ^ (l >> 3)) * 8;

  auto stage = [&](int p, int k0) {
#pragma unroll
    for (int j = 0; j < 2; ++j) {
      gl_lds16(Km + ((long)b * S + k0 + swr + 8 * j) * H + hh * 64 + swc,
               (char*)lK[p] + (w * 16 + 8 * j) * 128);
      gl_lds16(Vt + ((long)b * H + hh * 64 + swr + 8 * j) * S + k0 + swc,
               (char*)lV[p] + (w * 16 + 8 * j) * 128);
    }
    if (w == 0) gl_lds4(M2 + (long)b * S + k0 + l, (char*)lM[p]);
  };

  stage(0, kbase);
  __syncthreads();

  for (int t = 0; t < 16; ++t) {
    const int p = t & 1;
    if (t < 15) stage(p ^ 1, kbase + (t + 1) * 64);

    // init accumulators with shifted mask; reg r -> key (r&3)+8*(r>>2)+4*h32
    f32x16 s0, s1;
#pragma unroll
    for (int g = 0; g < 4; ++g) {
      const f32x4 m0 = *(const f32x4*)&lM[p][8 * g + 4 * h32];
      const f32x4 m1 = *(const f32x4*)&lM[p][32 + 8 * g + 4 * h32];
#pragma unroll
      for (int r = 0; r < 4; ++r) {
        s0[4 * g + r] = m0[r];
        s1[4 * g + r] = m1[r];
      }
    }

    // S = K Q^T (swapped); already exp2-scaled + shifted
    __builtin_amdgcn_s_setprio(1);
#pragma unroll
    for (int sl = 0; sl < 4; ++sl) {
      const int ch = sl * 2 + h32;
      const int cx = (ch ^ (q31 & 7)) * 16;
      const bf16x8 k0f = *(const bf16x8*)((const char*)lK[p] + q31 * 128 + cx);
      const bf16x8 k1f = *(const bf16x8*)((const char*)lK[p] + (32 + q31) * 128 + cx);
      s0 = MFMA32(k0f, qf[sl], s0);
      s1 = MFMA32(k1f, qf[sl], s1);
    }
    __builtin_amdgcn_s_setprio(0);

    // P = exp2(S) directly (fixed shift already applied)
#pragma unroll
    for (int i = 0; i < 16; ++i) s0[i] = __builtin_amdgcn_exp2f(s0[i]);
#pragma unroll
    for (int i = 0; i < 16; ++i) s1[i] = __builtin_amdgcn_exp2f(s1[i]);

    // P -> PV A-frags: cvt_pk + permlane32_swap (T12)
    bf16x8 pa[4];
#pragma unroll
    for (int ks = 0; ks < 4; ++ks) {
      const int rb = (ks & 1) * 8;
      unsigned a0, a1, b0, b1;
      if (ks < 2) {
        a0 = cvtpk_bf16(s0[rb + 0], s0[rb + 1]);
        a1 = cvtpk_bf16(s0[rb + 2], s0[rb + 3]);
        b0 = cvtpk_bf16(s0[rb + 4], s0[rb + 5]);
        b1 = cvtpk_bf16(s0[rb + 6], s0[rb + 7]);
      } else {
        a0 = cvtpk_bf16(s1[rb + 0], s1[rb + 1]);
        a1 = cvtpk_bf16(s1[rb + 2], s1[rb + 3]);
        b0 = cvtpk_bf16(s1[rb + 4], s1[rb + 5]);
        b1 = cvtpk_bf16(s1[rb + 6], s1[rb + 7]);
      }
      const u32x2 r02 = __builtin_amdgcn_permlane32_swap(a0, b0, false, false);
      const u32x2 r13 = __builtin_amdgcn_permlane32_swap(a1, b1, false, false);
      const u32x4 pw = {r02[0], r13[0], r02[1], r13[1]};
      pa[ks] = __builtin_bit_cast(bf16x8, pw);
    }

    // O += P V; l += P @ ones (on the MFMA pipe)
    __builtin_amdgcn_s_setprio(1);
#pragma unroll
    for (int ks = 0; ks < 4; ++ks) {
      const int ch = ks * 2 + h32;
      const int cx = (ch ^ (q31 & 7)) * 16;
      const bf16x8 v0 = *(const bf16x8*)((const char*)lV[p] + q31 * 128 + cx);
      const bf16x8 v1 = *(const bf16x8*)((const char*)lV[p] + (32 + q31) * 128 + cx);
      o0 = MFMA32(pa[ks], v0, o0);
      o1 = MFMA32(pa[ks], v1, o1);
      lsum = MFMA32(pa[ks], oneB, lsum);
    }
    __builtin_amdgcn_s_setprio(0);
    __syncthreads();
  }

  // epilogue: unnormalized O + l per (q,head,half). lsum's column 0 lives in
  // lanes with q31==0 (h32 selects which 16 rows).
  if (q31 == 0) {
#pragma unroll
    for (int reg = 0; reg < 16; ++reg) {
      const int row = (reg & 3) + 8 * (reg >> 2) + 4 * h32;
      ml[((long)half * 4096 + (long)b * 2048 + q0 + w * 32 + row) * 16 + hh] = lsum[reg];
    }
  }
#pragma unroll
  for (int reg = 0; reg < 16; ++reg) {
    const int row = (reg & 3) + 8 * (reg >> 2) + 4 * h32;
    const long qg = (long)b * 2048 + q0 + w * 32 + row;
    Opart[((long)half * 4096 + qg) * 1024 + hh * 64 + q31]      = (bf16)o0[reg];
    Opart[((long)half * 4096 + qg) * 1024 + hh * 64 + 32 + q31] = (bf16)o1[reg];
  }
}

// ---------------------------------------------------------------------------
extern "C" void kernel_launch(void* const* d_in, const int* in_sizes, int n_in,
                              void* d_out, int out_size, void* d_ws, size_t ws_size,
                              hipStream_t stream) {
  const float* X    = (const float*)d_in[0];
  const float* mask = (const float*)d_in[1];
  const float* Wq   = (const float*)d_in[2];  const float* bq  = (const float*)d_in[3];
  const float* Wk   = (const float*)d_in[4];  const float* bk  = (const float*)d_in[5];
  const float* Wv   = (const float*)d_in[6];  const float* bv  = (const float*)d_in[7];
  const float* Wo   = (const float*)d_in[8];  const float* bo  = (const float*)d_in[9];
  const float* mv   = (const float*)d_in[10];
  const float* Wmp  = (const float*)d_in[11]; const float* bmp = (const float*)d_in[12];
  const float* Wma  = (const float*)d_in[13]; const float* bma = (const float*)d_in[14];

  char* ws = (char*)d_ws;
  size_t off = 0;
  auto alloc = [&](size_t bytes) -> void* {
    void* p = ws + off;
    off += (bytes + 255) & ~(size_t)255;
    return p;
  };
  const long MS_ = 4096;
  bf16* Xb    = (bf16*)alloc(MS_ * 1024 * 2);
  bf16* Wqkvb = (bf16*)alloc(3328L * 1024 * 2);   // [Wq*QS | Wk | Wv | Wma]
  bf16* Wob   = (bf16*)alloc(1024 * 1024 * 2);
  bf16* Wmpb  = (bf16*)alloc(1024 * 512 * 2);
  bf16* mvTb  = (bf16*)alloc(512 * 256 * 2);
  float* M2   = (float*)alloc(MS_ * 4);
  float* bqkv = (float*)alloc(3328 * 4);
  bf16* Qb    = (bf16*)alloc(MS_ * 1024 * 2);
  bf16* Kb    = (bf16*)alloc(MS_ * 1024 * 2);
  bf16* Vtb   = (bf16*)alloc(MS_ * 1024 * 2);     // [B][h*64+d][S]
  bf16* Opart = (bf16*)alloc(2 * MS_ * 1024 * 2); // [2][4096][1024] = 16MB
  float* ml   = (float*)alloc(2 * MS_ * 16 * 4);  // [2][4096][16]
  float* MSc  = (float*)alloc(MS_ * 256 * 4);
  bf16* MP    = (bf16*)alloc(MS_ * 256 * 2);
  bf16* MO    = Kb;                               // dead after attn
  bf16* CB    = Qb;                               // dead after attn

  // 1: prep
  fused_prep<<<9480, 256, 0, stream>>>(X, Wq, Wk, Wv, Wo, Wma, Wmp, mask,
                                       bq, bk, bv, bma, mv,
                                       Xb, Wqkvb, Wob, Wmpb, M2, bqkv, mvTb);
  // 2: fused QKV + mem-score projection (XCD-swizzled flat grid, 4 blocks/CU)
  gemm_qkv<<<832, 256, 0, stream>>>(Xb, Wqkvb, bqkv, Qb, Kb, Vtb, MSc);
  // 3: attention, key-split x2 (combine deferred into gemm #5)
  attn_fwd<<<dim3(16, 16, 4), 256, 0, stream>>>(Qb, Kb, Vtb, M2, Opart, ml);
  // 4: mem-path softmax + probs @ mv^T
  softmax_rows256<<<1024, 256, 0, stream>>>(MSc, MP);
  gemm_bt<bf16, false><<<dim3(8, 32), 256, 0, stream>>>(MP, mvTb, nullptr, nullptr, nullptr,
                                                        MO, 4096, 512, 256, 1.0f);
  // 5: combined = 0.3*(mem_out @ Wmp^T + bmp) + combine(Opart, ml)
  gemm_bt<bf16, true><<<dim3(16, 32), 256, 0, stream>>>(MO, Wmpb, bmp, Opart, ml,
                                                        CB, 4096, 1024, 512, 0.3f);
  // 6: final projection -> fp32 out
  gemm_bt<float, false><<<dim3(16, 32), 256, 0, stream>>>(CB, Wob, bo, nullptr, nullptr,
                                                          (float*)d_out, 4096, 1024, 1024, 1.0f);
}

// Round 15
// 134.581 us; speedup vs baseline: 1.3881x; 1.3881x over previous
//
#include <hip/hip_runtime.h>

typedef __bf16 bf16;
typedef __bf16 bf16x8 __attribute__((ext_vector_type(8)));
typedef __bf16 bf16x4 __attribute__((ext_vector_type(4)));
typedef float  f32x4  __attribute__((ext_vector_type(4)));
typedef float  f32x16 __attribute__((ext_vector_type(16)));
typedef unsigned u32x2 __attribute__((ext_vector_type(2)));
typedef unsigned u32x4 __attribute__((ext_vector_type(4)));
typedef unsigned long long uptr;

#define MFMA16(a, b, c) __builtin_amdgcn_mfma_f32_16x16x32_bf16((a), (b), (c), 0, 0, 0)
#define MFMA32(a, b, c) __builtin_amdgcn_mfma_f32_32x32x16_bf16((a), (b), (c), 0, 0, 0)

__device__ __forceinline__ void gl_lds16(const void* g, void* l) {
  __builtin_amdgcn_global_load_lds(
      (__attribute__((address_space(1))) void*)(uptr)(g),
      (__attribute__((address_space(3))) void*)(uptr)(l),
      16, 0, 0);
}
__device__ __forceinline__ void gl_lds4(const void* g, void* l) {
  __builtin_amdgcn_global_load_lds(
      (__attribute__((address_space(1))) void*)(uptr)(g),
      (__attribute__((address_space(3))) void*)(uptr)(l),
      4, 0, 0);
}
__device__ __forceinline__ unsigned cvtpk_bf16(float lo, float hi) {
  unsigned r;
  asm("v_cvt_pk_bf16_f32 %0, %1, %2" : "=v"(r) : "v"(lo), "v"(hi));
  return r;
}

// ---------------------------------------------------------------------------
// Fused prep. Wq/bq PRE-SCALED by 0.125*log2(e). Wma appended to Wqkvb
// (rows 3072..3327) and bma to bqkv. M2 = mask*(-1e9*log2e) - 40 (fixed shift).
__global__ __launch_bounds__(256) void fused_prep(
    const float* __restrict__ X, const float* __restrict__ Wq,
    const float* __restrict__ Wk, const float* __restrict__ Wv,
    const float* __restrict__ Wo, const float* __restrict__ Wma,
    const float* __restrict__ Wmp, const float* __restrict__ mask,
    const float* __restrict__ bq, const float* __restrict__ bk,
    const float* __restrict__ bv, const float* __restrict__ bma,
    const float* __restrict__ mv,
    bf16* __restrict__ Xb, bf16* __restrict__ Wqkvb, bf16* __restrict__ Wob,
    bf16* __restrict__ Wmpb,
    float* __restrict__ M2, float* __restrict__ bqkv, bf16* __restrict__ mvTb) {
  const int bid = blockIdx.x, t = threadIdx.x;
  const float QS = 0.125f * 1.44269504f;
  auto cvt = [&](const float* src, bf16* dst, int blk, float sc) {
    const long i = ((long)blk * 256 + t) * 4;
    const float4 v = *(const float4*)(src + i);
    bf16x4 o = {(bf16)(v.x * sc), (bf16)(v.y * sc), (bf16)(v.z * sc), (bf16)(v.w * sc)};
    *(bf16x4*)(dst + i) = o;
  };
  if (bid < 4096) cvt(X, Xb, bid, 1.0f);
  else if (bid < 5120) cvt(Wq, Wqkvb, bid - 4096, QS);
  else if (bid < 6144) cvt(Wk, Wqkvb + 1024 * 1024, bid - 5120, 1.0f);
  else if (bid < 7168) cvt(Wv, Wqkvb + 2 * 1024 * 1024, bid - 6144, 1.0f);
  else if (bid < 8192) cvt(Wo, Wob, bid - 7168, 1.0f);
  else if (bid < 8448) cvt(Wma, Wqkvb + 3072 * 1024, bid - 8192, 1.0f);
  else if (bid < 8960) cvt(Wmp, Wmpb, bid - 8448, 1.0f);
  else if (bid < 8964) {
    const long i = ((long)(bid - 8960) * 256 + t) * 4;
    const float4 v = *(const float4*)(mask + i);
    float4 o = {v.x * -1.44269504e9f - 40.0f, v.y * -1.44269504e9f - 40.0f,
                v.z * -1.44269504e9f - 40.0f, v.w * -1.44269504e9f - 40.0f};
    *(float4*)(M2 + i) = o;
  } else if (bid < 8967) {
    const int s = bid - 8964;
    const float* src = s == 0 ? bq : (s == 1 ? bk : bv);
    const float sc = s == 0 ? QS : 1.0f;
    float4 v = *(const float4*)(src + t * 4);
    float4 o = {v.x * sc, v.y * sc, v.z * sc, v.w * sc};
    *(float4*)(bqkv + s * 1024 + t * 4) = o;
  } else if (bid < 8968) {
    if (t < 64) *(float4*)(bqkv + 3072 + t * 4) = *(const float4*)(bma + t * 4);
  } else {
    const int d = bid - 8968;
    mvTb[(long)d * 256 + t] = (bf16)mv[(long)t * 512 + d];
  }
}

// row softmax over 256 cols, fp32 in, bf16 out. one wave per row.
__global__ __launch_bounds__(256) void softmax_rows256(const float* __restrict__ in,
                                                       bf16* __restrict__ out) {
  const int w = threadIdx.x >> 6, l = threadIdx.x & 63;
  const long row = (long)blockIdx.x * 4 + w;
  const float4 v = *(const float4*)(in + row * 256 + l * 4);
  float mx = fmaxf(fmaxf(v.x, v.y), fmaxf(v.z, v.w));
  mx = fmaxf(mx, __shfl_xor(mx, 1, 64));
  mx = fmaxf(mx, __shfl_xor(mx, 2, 64));
  mx = fmaxf(mx, __shfl_xor(mx, 4, 64));
  mx = fmaxf(mx, __shfl_xor(mx, 8, 64));
  mx = fmaxf(mx, __shfl_xor(mx, 16, 64));
  mx = fmaxf(mx, __shfl_xor(mx, 32, 64));
  const float e0 = __expf(v.x - mx), e1 = __expf(v.y - mx);
  const float e2 = __expf(v.z - mx), e3 = __expf(v.w - mx);
  float sm = e0 + e1 + e2 + e3;
  sm += __shfl_xor(sm, 1, 64);
  sm += __shfl_xor(sm, 2, 64);
  sm += __shfl_xor(sm, 4, 64);
  sm += __shfl_xor(sm, 8, 64);
  sm += __shfl_xor(sm, 16, 64);
  sm += __shfl_xor(sm, 32, 64);
  const float inv = 1.0f / sm;
  bf16x4 o = {(bf16)(e0 * inv), (bf16)(e1 * inv), (bf16)(e2 * inv), (bf16)(e3 * inv)};
  *(bf16x4*)(out + row * 256 + l * 4) = o;
}

// ---------------------------------------------------------------------------
// Generic GEMM: C[M][N] = (A[M][K] @ B[N][K]^T + bias)*alpha (+ combine-add)
template <typename OutT, bool COMBINE>
__global__ __launch_bounds__(256, 3) void gemm_bt(
    const bf16* __restrict__ A, const bf16* __restrict__ B,
    const float* __restrict__ bias, const bf16* __restrict__ Op,
    const float* __restrict__ mlp, OutT* __restrict__ C,
    int M, int N, int K, float alpha) {
  __shared__ bf16 lA[2][128 * 64];
  __shared__ bf16 lB[2][64 * 64];
  const int tid = threadIdx.x;
  const int w = tid >> 6, l = tid & 63;
  const int hi = l >> 4, lo = l & 15;
  const int m0 = blockIdx.y * 128, n0 = blockIdx.x * 64;
  const int wm = w * 32;

  const int sr8 = l >> 3;
  const int sc = (l & 7) * 8;
  const long aRow = (long)(m0 + wm + sr8);
  const long bRow = (long)(n0 + w * 16 + sr8);

  auto stage = [&](int p, int k0) {
#pragma unroll
    for (int j = 0; j < 4; ++j)
      gl_lds16(A + (aRow + 8 * j) * K + k0 + sc, (char*)lA[p] + (wm + 8 * j) * 128);
#pragma unroll
    for (int j = 0; j < 2; ++j)
      gl_lds16(B + (bRow + 8 * j) * K + k0 + sc, (char*)lB[p] + (w * 16 + 8 * j) * 128);
  };

  f32x4 acc[2][4] = {};
  stage(0, 0);
  __syncthreads();
  const int nt = K >> 6;

  for (int t = 0; t < nt; ++t) {
    const int p = t & 1;
    if (t + 1 < nt) stage(p ^ 1, (t + 1) << 6);
#pragma unroll
    for (int kk = 0; kk < 2; ++kk) {
      bf16x8 af[2], bfr[4];
#pragma unroll
      for (int mi = 0; mi < 2; ++mi)
        af[mi] = *(const bf16x8*)((const char*)lA[p] + (wm + mi * 16 + lo) * 128 + kk * 64 + hi * 16);
#pragma unroll
      for (int ni = 0; ni < 4; ++ni)
        bfr[ni] = *(const bf16x8*)((const char*)lB[p] + (ni * 16 + lo) * 128 + kk * 64 + hi * 16);
      __builtin_amdgcn_s_setprio(1);
#pragma unroll
      for (int mi = 0; mi < 2; ++mi)
#pragma unroll
        for (int ni = 0; ni < 4; ++ni)
          acc[mi][ni] = MFMA16(af[mi], bfr[ni], acc[mi][ni]);
      __builtin_amdgcn_s_setprio(0);
    }
    __syncthreads();
  }

#pragma unroll
  for (int ni = 0; ni < 4; ++ni) {
    const int col = n0 + ni * 16 + lo;
    const float bv = bias ? bias[col] : 0.0f;
#pragma unroll
    for (int mi = 0; mi < 2; ++mi) {
      const int mrow = m0 + wm + mi * 16 + hi * 4;
#pragma unroll
      for (int r = 0; r < 4; ++r) {
        const long row = mrow + r;
        float v = (acc[mi][ni][r] + bv) * alpha;
        if (COMBINE) {
          const int h = col >> 6;
          const float l0 = mlp[row * 16 + h];
          const float l1 = mlp[(4096L + row) * 16 + h];
          const float o0v = (float)Op[row * 1024 + col];
          const float o1v = (float)Op[4096L * 1024 + row * 1024 + col];
          v += (o0v + o1v) / (l0 + l1);
        }
        C[row * (long)N + col] = (OutT)v;
      }
    }
  }
}

// Fused QKV + mem-score projection, m97 128x128 structure, 4 blocks/CU,
// XCD-swizzled flat grid (832 = 8 XCD x 104; consecutive roles share B-panel).
__global__ __launch_bounds__(256, 4) void gemm_qkv(
    const bf16* __restrict__ A, const bf16* __restrict__ B,
    const float* __restrict__ bias, bf16* __restrict__ Qo,
    bf16* __restrict__ Ko, bf16* __restrict__ Vto, float* __restrict__ MSc) {
  const int K = 1024;
  __shared__ bf16 smem[2][128 * 64];   // lA | lB; reused as transpose buf
  bf16* lA = smem[0];
  bf16* lB = smem[1];
  const int lin = blockIdx.x;
  const int role = (lin & 7) * 104 + (lin >> 3);   // 832/8 = 104 per XCD
  const int m0 = (role & 31) * 128;                // m fastest within XCD
  const int n0 = (role >> 5) * 128;
  const int tid = threadIdx.x;
  const int w = tid >> 6, l = tid & 63;
  const int hi = l >> 4, lo = l & 15;
  const int wm = (w >> 1) * 64, wn = (w & 1) * 64;

  const int sr = w * 32 + (l >> 3);
  const int sc = (l & 7) * 8;
  const long aBase = (long)(m0 + sr) * K + sc;
  const long bBase = (long)(n0 + sr) * K + sc;

  f32x4 acc[4][4] = {};

  for (int k0 = 0; k0 < K; k0 += 64) {
#pragma unroll
    for (int j = 0; j < 4; ++j) {
      gl_lds16(A + aBase + (long)8 * j * K + k0, (char*)lA + (w * 32 + 8 * j) * 128);
      gl_lds16(B + bBase + (long)8 * j * K + k0, (char*)lB + (w * 32 + 8 * j) * 128);
    }
    __syncthreads();
#pragma unroll
    for (int kk = 0; kk < 2; ++kk) {
      bf16x8 af[4], bfr[4];
#pragma unroll
      for (int i = 0; i < 4; ++i) {
        af[i]  = *(const bf16x8*)((const char*)lA + (wm + i * 16 + lo) * 128 + kk * 64 + hi * 16);
        bfr[i] = *(const bf16x8*)((const char*)lB + (wn + i * 16 + lo) * 128 + kk * 64 + hi * 16);
      }
#pragma unroll
      for (int mi = 0; mi < 4; ++mi)
#pragma unroll
        for (int ni = 0; ni < 4; ++ni)
          acc[mi][ni] = MFMA16(af[mi], bfr[ni], acc[mi][ni]);
    }
    __syncthreads();
  }

  if (n0 < 2048) {       // Q or K
#pragma unroll
    for (int ni = 0; ni < 4; ++ni) {
      const int col = n0 + wn + ni * 16 + lo;
      const float bv = bias[col];
#pragma unroll
      for (int mi = 0; mi < 4; ++mi) {
        const int mrow = m0 + wm + mi * 16 + hi * 4;
#pragma unroll
        for (int r = 0; r < 4; ++r) {
          const long row = mrow + r;
          const float v = acc[mi][ni][r] + bv;
          if (n0 < 1024) Qo[row * 1024 + col] = (bf16)v;
          else           Ko[row * 1024 + (col - 1024)] = (bf16)v;
        }
      }
    }
  } else if (n0 < 3072) {  // V: transpose through LDS, coalesced Vt writes
    bf16* sT = smem[0];
#pragma unroll
    for (int ni = 0; ni < 4; ++ni) {
      const int cT = wn + ni * 16 + lo;
      const float bv = bias[n0 + cT];
#pragma unroll
      for (int mi = 0; mi < 4; ++mi) {
        const int rT = wm + mi * 16 + hi * 4;
        u32x2 pw = {cvtpk_bf16(acc[mi][ni][0] + bv, acc[mi][ni][1] + bv),
                    cvtpk_bf16(acc[mi][ni][2] + bv, acc[mi][ni][3] + bv)};
        *(u32x2*)((char*)sT + cT * 256 + ((rT * 2) ^ ((cT & 15) << 3))) = pw;
      }
    }
    __syncthreads();
    const long vrow0 = (long)(m0 >> 11) * 1024 + (n0 - 2048);
    const int srow = m0 & 2047;
#pragma unroll
    for (int dd = 0; dd < 32; ++dd) {
      const int d = w * 32 + dd;
      const unsigned pv = *(const unsigned*)((const char*)sT + d * 256 + ((l * 4) ^ ((d & 15) << 3)));
      *(unsigned*)((char*)(Vto + (vrow0 + d) * 2048 + srow) + l * 4) = pv;
    }
  } else {               // mem-scores -> MSc fp32 [4096][256]
#pragma unroll
    for (int ni = 0; ni < 4; ++ni) {
      const int col = n0 + wn + ni * 16 + lo;
      const float bv = bias[col];
      const int cm = col - 3072;
#pragma unroll
      for (int mi = 0; mi < 4; ++mi) {
        const int mrow = m0 + wm + mi * 16 + hi * 4;
#pragma unroll
        for (int r = 0; r < 4; ++r)
          MSc[(long)(mrow + r) * 256 + cm] = acc[mi][ni][r] + bv;
      }
    }
  }
}

// ---------------------------------------------------------------------------
// Flash attention, swapped-QK^T 32x32, KEY-SPLIT x2, FIXED-SHIFT softmax.
// (R9 version: mask staged one tile ahead into LDS via gl_lds4; VALU row-sum.)
__global__ __launch_bounds__(256, 4) void attn_fwd(
    const bf16* __restrict__ Q, const bf16* __restrict__ Km,
    const bf16* __restrict__ Vt, const float* __restrict__ M2,
    bf16* __restrict__ Opart, float* __restrict__ ml) {
  __shared__ bf16 lK[2][64 * 64];
  __shared__ bf16 lV[2][64 * 64];
  __shared__ alignas(16) float lM[2][64];
  const int tid = threadIdx.x, w = tid >> 6, l = tid & 63;
  const int q31 = l & 31, h32 = l >> 5;
  const int b = blockIdx.z >> 1, half = blockIdx.z & 1;
  const int hh = blockIdx.y, q0 = blockIdx.x * 128;
  const long S = 2048, H = 1024;
  const int kbase = half * 1024;

  bf16x8 qf[4];
  const long qrow = (long)b * S + q0 + w * 32 + q31;
#pragma unroll
  for (int sl = 0; sl < 4; ++sl)
    qf[sl] = *(const bf16x8*)(Q + qrow * H + hh * 64 + sl * 16 + h32 * 8);

  f32x16 o0 = {}, o1 = {};
  float lrun = 0.0f;

  const int swr = w * 16 + (l >> 3);
  const int swc = ((l & 7) ^ (l >> 3)) * 8;

  auto stage = [&](int p, int k0) {
#pragma unroll
    for (int j = 0; j < 2; ++j) {
      gl_lds16(Km + ((long)b * S + k0 + swr + 8 * j) * H + hh * 64 + swc,
               (char*)lK[p] + (w * 16 + 8 * j) * 128);
      gl_lds16(Vt + ((long)b * H + hh * 64 + swr + 8 * j) * S + k0 + swc,
               (char*)lV[p] + (w * 16 + 8 * j) * 128);
    }
    if (w == 0) gl_lds4(M2 + (long)b * S + k0 + l, (char*)lM[p]);
  };

  stage(0, kbase);
  __syncthreads();

  for (int t = 0; t < 16; ++t) {
    const int p = t & 1;
    if (t < 15) stage(p ^ 1, kbase + (t + 1) * 64);

    // init accumulators with shifted mask; reg r -> key (r&3)+8*(r>>2)+4*h32
    f32x16 s0, s1;
#pragma unroll
    for (int g = 0; g < 4; ++g) {
      const f32x4 m0 = *(const f32x4*)&lM[p][8 * g + 4 * h32];
      const f32x4 m1 = *(const f32x4*)&lM[p][32 + 8 * g + 4 * h32];
#pragma unroll
      for (int r = 0; r < 4; ++r) {
        s0[4 * g + r] = m0[r];
        s1[4 * g + r] = m1[r];
      }
    }

    // S = K Q^T (swapped); already exp2-scaled + shifted
    __builtin_amdgcn_s_setprio(1);
#pragma unroll
    for (int sl = 0; sl < 4; ++sl) {
      const int ch = sl * 2 + h32;
      const int cx = (ch ^ (q31 & 7)) * 16;
      const bf16x8 k0f = *(const bf16x8*)((const char*)lK[p] + q31 * 128 + cx);
      const bf16x8 k1f = *(const bf16x8*)((const char*)lK[p] + (32 + q31) * 128 + cx);
      s0 = MFMA32(k0f, qf[sl], s0);
      s1 = MFMA32(k1f, qf[sl], s1);
    }
    __builtin_amdgcn_s_setprio(0);

    // P = exp2(S) directly (fixed shift already applied)
#pragma unroll
    for (int i = 0; i < 16; ++i) s0[i] = __builtin_amdgcn_exp2f(s0[i]);
#pragma unroll
    for (int i = 0; i < 16; ++i) s1[i] = __builtin_amdgcn_exp2f(s1[i]);

    // row sum: in-lane tree + one cross-half shuffle
    f32x16 ts;
#pragma unroll
    for (int i = 0; i < 16; ++i) ts[i] = s0[i] + s1[i];
#pragma unroll
    for (int i = 0; i < 8; ++i) ts[i] += ts[i + 8];
#pragma unroll
    for (int i = 0; i < 4; ++i) ts[i] += ts[i + 4];
    float rs = (ts[0] + ts[1]) + (ts[2] + ts[3]);
    rs += __shfl_xor(rs, 32, 64);
    lrun += rs;

    // P -> PV A-frags: cvt_pk + permlane32_swap (T12)
    bf16x8 pa[4];
#pragma unroll
    for (int ks = 0; ks < 4; ++ks) {
      const int rb = (ks & 1) * 8;
      unsigned a0, a1, b0, b1;
      if (ks < 2) {
        a0 = cvtpk_bf16(s0[rb + 0], s0[rb + 1]);
        a1 = cvtpk_bf16(s0[rb + 2], s0[rb + 3]);
        b0 = cvtpk_bf16(s0[rb + 4], s0[rb + 5]);
        b1 = cvtpk_bf16(s0[rb + 6], s0[rb + 7]);
      } else {
        a0 = cvtpk_bf16(s1[rb + 0], s1[rb + 1]);
        a1 = cvtpk_bf16(s1[rb + 2], s1[rb + 3]);
        b0 = cvtpk_bf16(s1[rb + 4], s1[rb + 5]);
        b1 = cvtpk_bf16(s1[rb + 6], s1[rb + 7]);
      }
      const u32x2 r02 = __builtin_amdgcn_permlane32_swap(a0, b0, false, false);
      const u32x2 r13 = __builtin_amdgcn_permlane32_swap(a1, b1, false, false);
      const u32x4 pw = {r02[0], r13[0], r02[1], r13[1]};
      pa[ks] = __builtin_bit_cast(bf16x8, pw);
    }

    // O += P V
    __builtin_amdgcn_s_setprio(1);
#pragma unroll
    for (int ks = 0; ks < 4; ++ks) {
      const int ch = ks * 2 + h32;
      const int cx = (ch ^ (q31 & 7)) * 16;
      const bf16x8 v0 = *(const bf16x8*)((const char*)lV[p] + q31 * 128 + cx);
      const bf16x8 v1 = *(const bf16x8*)((const char*)lV[p] + (32 + q31) * 128 + cx);
      o0 = MFMA32(pa[ks], v0, o0);
      o1 = MFMA32(pa[ks], v1, o1);
    }
    __builtin_amdgcn_s_setprio(0);
    __syncthreads();
  }

  // epilogue: unnormalized O + l per (q,head,half)
  if (h32 == 0)
    ml[((long)half * 4096 + (long)b * 2048 + q0 + w * 32 + q31) * 16 + hh] = lrun;
#pragma unroll
  for (int reg = 0; reg < 16; ++reg) {
    const int row = (reg & 3) + 8 * (reg >> 2) + 4 * h32;
    const long qg = (long)b * 2048 + q0 + w * 32 + row;
    Opart[((long)half * 4096 + qg) * 1024 + hh * 64 + q31]      = (bf16)o0[reg];
    Opart[((long)half * 4096 + qg) * 1024 + hh * 64 + 32 + q31] = (bf16)o1[reg];
  }
}

// ---------------------------------------------------------------------------
extern "C" void kernel_launch(void* const* d_in, const int* in_sizes, int n_in,
                              void* d_out, int out_size, void* d_ws, size_t ws_size,
                              hipStream_t stream) {
  const float* X    = (const float*)d_in[0];
  const float* mask = (const float*)d_in[1];
  const float* Wq   = (const float*)d_in[2];  const float* bq  = (const float*)d_in[3];
  const float* Wk   = (const float*)d_in[4];  const float* bk  = (const float*)d_in[5];
  const float* Wv   = (const float*)d_in[6];  const float* bv  = (const float*)d_in[7];
  const float* Wo   = (const float*)d_in[8];  const float* bo  = (const float*)d_in[9];
  const float* mv   = (const float*)d_in[10];
  const float* Wmp  = (const float*)d_in[11]; const float* bmp = (const float*)d_in[12];
  const float* Wma  = (const float*)d_in[13]; const float* bma = (const float*)d_in[14];

  char* ws = (char*)d_ws;
  size_t off = 0;
  auto alloc = [&](size_t bytes) -> void* {
    void* p = ws + off;
    off += (bytes + 255) & ~(size_t)255;
    return p;
  };
  const long MS_ = 4096;
  bf16* Xb    = (bf16*)alloc(MS_ * 1024 * 2);
  bf16* Wqkvb = (bf16*)alloc(3328L * 1024 * 2);   // [Wq*QS | Wk | Wv | Wma]
  bf16* Wob   = (bf16*)alloc(1024 * 1024 * 2);
  bf16* Wmpb  = (bf16*)alloc(1024 * 512 * 2);
  bf16* mvTb  = (bf16*)alloc(512 * 256 * 2);
  float* M2   = (float*)alloc(MS_ * 4);
  float* bqkv = (float*)alloc(3328 * 4);
  bf16* Qb    = (bf16*)alloc(MS_ * 1024 * 2);
  bf16* Kb    = (bf16*)alloc(MS_ * 1024 * 2);
  bf16* Vtb   = (bf16*)alloc(MS_ * 1024 * 2);     // [B][h*64+d][S]
  bf16* Opart = (bf16*)alloc(2 * MS_ * 1024 * 2); // [2][4096][1024] = 16MB
  float* ml   = (float*)alloc(2 * MS_ * 16 * 4);  // [2][4096][16]
  float* MSc  = (float*)alloc(MS_ * 256 * 4);
  bf16* MP    = (bf16*)alloc(MS_ * 256 * 2);
  bf16* MO    = Kb;                               // dead after attn
  bf16* CB    = Qb;                               // dead after attn

  // 1: prep
  fused_prep<<<9480, 256, 0, stream>>>(X, Wq, Wk, Wv, Wo, Wma, Wmp, mask,
                                       bq, bk, bv, bma, mv,
                                       Xb, Wqkvb, Wob, Wmpb, M2, bqkv, mvTb);
  // 2: fused QKV + mem-score projection (XCD-swizzled flat grid, 4 blocks/CU)
  gemm_qkv<<<832, 256, 0, stream>>>(Xb, Wqkvb, bqkv, Qb, Kb, Vtb, MSc);
  // 3: attention, key-split x2 (combine deferred into gemm #5)
  attn_fwd<<<dim3(16, 16, 4), 256, 0, stream>>>(Qb, Kb, Vtb, M2, Opart, ml);
  // 4: mem-path softmax + probs @ mv^T
  softmax_rows256<<<1024, 256, 0, stream>>>(MSc, MP);
  gemm_bt<bf16, false><<<dim3(8, 32), 256, 0, stream>>>(MP, mvTb, nullptr, nullptr, nullptr,
                                                        MO, 4096, 512, 256, 1.0f);
  // 5: combined = 0.3*(mem_out @ Wmp^T + bmp) + combine(Opart, ml)
  gemm_bt<bf16, true><<<dim3(16, 32), 256, 0, stream>>>(MO, Wmpb, bmp, Opart, ml,
                                                        CB, 4096, 1024, 512, 0.3f);
  // 6: final projection -> fp32 out
  gemm_bt<float, false><<<dim3(16, 32), 256, 0, stream>>>(CB, Wob, bo, nullptr, nullptr,
                                                          (float*)d_out, 4096, 1024, 1024, 1.0f);
}

// Round 16
// 134.177 us; speedup vs baseline: 1.3923x; 1.0030x over previous
//
#include <hip/hip_runtime.h>

typedef __bf16 bf16;
typedef __bf16 bf16x8 __attribute__((ext_vector_type(8)));
typedef __bf16 bf16x4 __attribute__((ext_vector_type(4)));
typedef float  f32x4  __attribute__((ext_vector_type(4)));
typedef float  f32x16 __attribute__((ext_vector_type(16)));
typedef unsigned u32x2 __attribute__((ext_vector_type(2)));
typedef unsigned u32x4 __attribute__((ext_vector_type(4)));
typedef unsigned long long uptr;

#define MFMA16(a, b, c) __builtin_amdgcn_mfma_f32_16x16x32_bf16((a), (b), (c), 0, 0, 0)
#define MFMA32(a, b, c) __builtin_amdgcn_mfma_f32_32x32x16_bf16((a), (b), (c), 0, 0, 0)

__device__ __forceinline__ void gl_lds16(const void* g, void* l) {
  __builtin_amdgcn_global_load_lds(
      (__attribute__((address_space(1))) void*)(uptr)(g),
      (__attribute__((address_space(3))) void*)(uptr)(l),
      16, 0, 0);
}
__device__ __forceinline__ void gl_lds4(const void* g, void* l) {
  __builtin_amdgcn_global_load_lds(
      (__attribute__((address_space(1))) void*)(uptr)(g),
      (__attribute__((address_space(3))) void*)(uptr)(l),
      4, 0, 0);
}
__device__ __forceinline__ unsigned cvtpk_bf16(float lo, float hi) {
  unsigned r;
  asm("v_cvt_pk_bf16_f32 %0, %1, %2" : "=v"(r) : "v"(lo), "v"(hi));
  return r;
}

// ---------------------------------------------------------------------------
// Fused prep. Wq/bq PRE-SCALED by 0.125*log2(e). Wma appended to Wqkvb
// (rows 3072..3327) and bma to bqkv. M2 = mask*(-1e9*log2e) - 40 (fixed shift).
__global__ __launch_bounds__(256) void fused_prep(
    const float* __restrict__ X, const float* __restrict__ Wq,
    const float* __restrict__ Wk, const float* __restrict__ Wv,
    const float* __restrict__ Wo, const float* __restrict__ Wma,
    const float* __restrict__ Wmp, const float* __restrict__ mask,
    const float* __restrict__ bq, const float* __restrict__ bk,
    const float* __restrict__ bv, const float* __restrict__ bma,
    const float* __restrict__ mv,
    bf16* __restrict__ Xb, bf16* __restrict__ Wqkvb, bf16* __restrict__ Wob,
    bf16* __restrict__ Wmpb,
    float* __restrict__ M2, float* __restrict__ bqkv, bf16* __restrict__ mvTb) {
  const int bid = blockIdx.x, t = threadIdx.x;
  const float QS = 0.125f * 1.44269504f;
  auto cvt = [&](const float* src, bf16* dst, int blk, float sc) {
    const long i = ((long)blk * 256 + t) * 4;
    const float4 v = *(const float4*)(src + i);
    bf16x4 o = {(bf16)(v.x * sc), (bf16)(v.y * sc), (bf16)(v.z * sc), (bf16)(v.w * sc)};
    *(bf16x4*)(dst + i) = o;
  };
  if (bid < 4096) cvt(X, Xb, bid, 1.0f);
  else if (bid < 5120) cvt(Wq, Wqkvb, bid - 4096, QS);
  else if (bid < 6144) cvt(Wk, Wqkvb + 1024 * 1024, bid - 5120, 1.0f);
  else if (bid < 7168) cvt(Wv, Wqkvb + 2 * 1024 * 1024, bid - 6144, 1.0f);
  else if (bid < 8192) cvt(Wo, Wob, bid - 7168, 1.0f);
  else if (bid < 8448) cvt(Wma, Wqkvb + 3072 * 1024, bid - 8192, 1.0f);
  else if (bid < 8960) cvt(Wmp, Wmpb, bid - 8448, 1.0f);
  else if (bid < 8964) {
    const long i = ((long)(bid - 8960) * 256 + t) * 4;
    const float4 v = *(const float4*)(mask + i);
    float4 o = {v.x * -1.44269504e9f - 40.0f, v.y * -1.44269504e9f - 40.0f,
                v.z * -1.44269504e9f - 40.0f, v.w * -1.44269504e9f - 40.0f};
    *(float4*)(M2 + i) = o;
  } else if (bid < 8967) {
    const int s = bid - 8964;
    const float* src = s == 0 ? bq : (s == 1 ? bk : bv);
    const float sc = s == 0 ? QS : 1.0f;
    float4 v = *(const float4*)(src + t * 4);
    float4 o = {v.x * sc, v.y * sc, v.z * sc, v.w * sc};
    *(float4*)(bqkv + s * 1024 + t * 4) = o;
  } else if (bid < 8968) {
    if (t < 64) *(float4*)(bqkv + 3072 + t * 4) = *(const float4*)(bma + t * 4);
  } else {
    const int d = bid - 8968;
    mvTb[(long)d * 256 + t] = (bf16)mv[(long)t * 512 + d];
  }
}

// row softmax over 256 cols, fp32 in, bf16 out. one wave per row.
__global__ __launch_bounds__(256) void softmax_rows256(const float* __restrict__ in,
                                                       bf16* __restrict__ out) {
  const int w = threadIdx.x >> 6, l = threadIdx.x & 63;
  const long row = (long)blockIdx.x * 4 + w;
  const float4 v = *(const float4*)(in + row * 256 + l * 4);
  float mx = fmaxf(fmaxf(v.x, v.y), fmaxf(v.z, v.w));
  mx = fmaxf(mx, __shfl_xor(mx, 1, 64));
  mx = fmaxf(mx, __shfl_xor(mx, 2, 64));
  mx = fmaxf(mx, __shfl_xor(mx, 4, 64));
  mx = fmaxf(mx, __shfl_xor(mx, 8, 64));
  mx = fmaxf(mx, __shfl_xor(mx, 16, 64));
  mx = fmaxf(mx, __shfl_xor(mx, 32, 64));
  const float e0 = __expf(v.x - mx), e1 = __expf(v.y - mx);
  const float e2 = __expf(v.z - mx), e3 = __expf(v.w - mx);
  float sm = e0 + e1 + e2 + e3;
  sm += __shfl_xor(sm, 1, 64);
  sm += __shfl_xor(sm, 2, 64);
  sm += __shfl_xor(sm, 4, 64);
  sm += __shfl_xor(sm, 8, 64);
  sm += __shfl_xor(sm, 16, 64);
  sm += __shfl_xor(sm, 32, 64);
  const float inv = 1.0f / sm;
  bf16x4 o = {(bf16)(e0 * inv), (bf16)(e1 * inv), (bf16)(e2 * inv), (bf16)(e3 * inv)};
  *(bf16x4*)(out + row * 256 + l * 4) = o;
}

// ---------------------------------------------------------------------------
// Generic GEMM: C[M][N] = (A[M][K] @ B[N][K]^T + bias)*alpha (+ combine-add)
// COMBINE: the attention key-half merge fused into the epilogue. The head
// index h = n0>>6 is block-uniform, so l0/l1 loads + reciprocal hoist out of
// the per-column loops (8 rcp/thread instead of 32).
template <typename OutT, bool COMBINE>
__global__ __launch_bounds__(256, 3) void gemm_bt(
    const bf16* __restrict__ A, const bf16* __restrict__ B,
    const float* __restrict__ bias, const bf16* __restrict__ Op,
    const float* __restrict__ mlp, OutT* __restrict__ C,
    int M, int N, int K, float alpha) {
  __shared__ bf16 lA[2][128 * 64];
  __shared__ bf16 lB[2][64 * 64];
  const int tid = threadIdx.x;
  const int w = tid >> 6, l = tid & 63;
  const int hi = l >> 4, lo = l & 15;
  const int m0 = blockIdx.y * 128, n0 = blockIdx.x * 64;
  const int wm = w * 32;

  const int sr8 = l >> 3;
  const int sc = (l & 7) * 8;
  const long aRow = (long)(m0 + wm + sr8);
  const long bRow = (long)(n0 + w * 16 + sr8);

  auto stage = [&](int p, int k0) {
#pragma unroll
    for (int j = 0; j < 4; ++j)
      gl_lds16(A + (aRow + 8 * j) * K + k0 + sc, (char*)lA[p] + (wm + 8 * j) * 128);
#pragma unroll
    for (int j = 0; j < 2; ++j)
      gl_lds16(B + (bRow + 8 * j) * K + k0 + sc, (char*)lB[p] + (w * 16 + 8 * j) * 128);
  };

  f32x4 acc[2][4] = {};
  stage(0, 0);
  __syncthreads();
  const int nt = K >> 6;

  for (int t = 0; t < nt; ++t) {
    const int p = t & 1;
    if (t + 1 < nt) stage(p ^ 1, (t + 1) << 6);
#pragma unroll
    for (int kk = 0; kk < 2; ++kk) {
      bf16x8 af[2], bfr[4];
#pragma unroll
      for (int mi = 0; mi < 2; ++mi)
        af[mi] = *(const bf16x8*)((const char*)lA[p] + (wm + mi * 16 + lo) * 128 + kk * 64 + hi * 16);
#pragma unroll
      for (int ni = 0; ni < 4; ++ni)
        bfr[ni] = *(const bf16x8*)((const char*)lB[p] + (ni * 16 + lo) * 128 + kk * 64 + hi * 16);
      __builtin_amdgcn_s_setprio(1);
#pragma unroll
      for (int mi = 0; mi < 2; ++mi)
#pragma unroll
        for (int ni = 0; ni < 4; ++ni)
          acc[mi][ni] = MFMA16(af[mi], bfr[ni], acc[mi][ni]);
      __builtin_amdgcn_s_setprio(0);
    }
    __syncthreads();
  }

  // COMBINE: per-row normalization factor, hoisted (h is block-uniform)
  float cinv[2][4];
  if (COMBINE) {
    const int h = n0 >> 6;
#pragma unroll
    for (int mi = 0; mi < 2; ++mi)
#pragma unroll
      for (int r = 0; r < 4; ++r) {
        const long row = m0 + wm + mi * 16 + hi * 4 + r;
        cinv[mi][r] = 1.0f / (mlp[row * 16 + h] + mlp[(4096L + row) * 16 + h]);
      }
  }

#pragma unroll
  for (int ni = 0; ni < 4; ++ni) {
    const int col = n0 + ni * 16 + lo;
    const float bv = bias ? bias[col] : 0.0f;
#pragma unroll
    for (int mi = 0; mi < 2; ++mi) {
      const int mrow = m0 + wm + mi * 16 + hi * 4;
#pragma unroll
      for (int r = 0; r < 4; ++r) {
        const long row = mrow + r;
        float v = (acc[mi][ni][r] + bv) * alpha;
        if (COMBINE) {
          const float o0v = (float)Op[row * 1024 + col];
          const float o1v = (float)Op[4096L * 1024 + row * 1024 + col];
          v += (o0v + o1v) * cinv[mi][r];
        }
        C[row * (long)N + col] = (OutT)v;
      }
    }
  }
}

// Fused QKV + mem-score projection, m97 128x128 structure, 4 blocks/CU,
// XCD-swizzled flat grid (832 = 8 XCD x 104; consecutive roles share B-panel).
__global__ __launch_bounds__(256, 4) void gemm_qkv(
    const bf16* __restrict__ A, const bf16* __restrict__ B,
    const float* __restrict__ bias, bf16* __restrict__ Qo,
    bf16* __restrict__ Ko, bf16* __restrict__ Vto, float* __restrict__ MSc) {
  const int K = 1024;
  __shared__ bf16 smem[2][128 * 64];   // lA | lB; reused as transpose buf
  bf16* lA = smem[0];
  bf16* lB = smem[1];
  const int lin = blockIdx.x;
  const int role = (lin & 7) * 104 + (lin >> 3);   // 832/8 = 104 per XCD
  const int m0 = (role & 31) * 128;                // m fastest within XCD
  const int n0 = (role >> 5) * 128;
  const int tid = threadIdx.x;
  const int w = tid >> 6, l = tid & 63;
  const int hi = l >> 4, lo = l & 15;
  const int wm = (w >> 1) * 64, wn = (w & 1) * 64;

  const int sr = w * 32 + (l >> 3);
  const int sc = (l & 7) * 8;
  const long aBase = (long)(m0 + sr) * K + sc;
  const long bBase = (long)(n0 + sr) * K + sc;

  f32x4 acc[4][4] = {};

  for (int k0 = 0; k0 < K; k0 += 64) {
#pragma unroll
    for (int j = 0; j < 4; ++j) {
      gl_lds16(A + aBase + (long)8 * j * K + k0, (char*)lA + (w * 32 + 8 * j) * 128);
      gl_lds16(B + bBase + (long)8 * j * K + k0, (char*)lB + (w * 32 + 8 * j) * 128);
    }
    __syncthreads();
#pragma unroll
    for (int kk = 0; kk < 2; ++kk) {
      bf16x8 af[4], bfr[4];
#pragma unroll
      for (int i = 0; i < 4; ++i) {
        af[i]  = *(const bf16x8*)((const char*)lA + (wm + i * 16 + lo) * 128 + kk * 64 + hi * 16);
        bfr[i] = *(const bf16x8*)((const char*)lB + (wn + i * 16 + lo) * 128 + kk * 64 + hi * 16);
      }
#pragma unroll
      for (int mi = 0; mi < 4; ++mi)
#pragma unroll
        for (int ni = 0; ni < 4; ++ni)
          acc[mi][ni] = MFMA16(af[mi], bfr[ni], acc[mi][ni]);
    }
    __syncthreads();
  }

  if (n0 < 2048) {       // Q or K
#pragma unroll
    for (int ni = 0; ni < 4; ++ni) {
      const int col = n0 + wn + ni * 16 + lo;
      const float bv = bias[col];
#pragma unroll
      for (int mi = 0; mi < 4; ++mi) {
        const int mrow = m0 + wm + mi * 16 + hi * 4;
#pragma unroll
        for (int r = 0; r < 4; ++r) {
          const long row = mrow + r;
          const float v = acc[mi][ni][r] + bv;
          if (n0 < 1024) Qo[row * 1024 + col] = (bf16)v;
          else           Ko[row * 1024 + (col - 1024)] = (bf16)v;
        }
      }
    }
  } else if (n0 < 3072) {  // V: transpose through LDS, coalesced Vt writes
    bf16* sT = smem[0];
#pragma unroll
    for (int ni = 0; ni < 4; ++ni) {
      const int cT = wn + ni * 16 + lo;
      const float bv = bias[n0 + cT];
#pragma unroll
      for (int mi = 0; mi < 4; ++mi) {
        const int rT = wm + mi * 16 + hi * 4;
        u32x2 pw = {cvtpk_bf16(acc[mi][ni][0] + bv, acc[mi][ni][1] + bv),
                    cvtpk_bf16(acc[mi][ni][2] + bv, acc[mi][ni][3] + bv)};
        *(u32x2*)((char*)sT + cT * 256 + ((rT * 2) ^ ((cT & 15) << 3))) = pw;
      }
    }
    __syncthreads();
    const long vrow0 = (long)(m0 >> 11) * 1024 + (n0 - 2048);
    const int srow = m0 & 2047;
#pragma unroll
    for (int dd = 0; dd < 32; ++dd) {
      const int d = w * 32 + dd;
      const unsigned pv = *(const unsigned*)((const char*)sT + d * 256 + ((l * 4) ^ ((d & 15) << 3)));
      *(unsigned*)((char*)(Vto + (vrow0 + d) * 2048 + srow) + l * 4) = pv;
    }
  } else {               // mem-scores -> MSc fp32 [4096][256]
#pragma unroll
    for (int ni = 0; ni < 4; ++ni) {
      const int col = n0 + wn + ni * 16 + lo;
      const float bv = bias[col];
      const int cm = col - 3072;
#pragma unroll
      for (int mi = 0; mi < 4; ++mi) {
        const int mrow = m0 + wm + mi * 16 + hi * 4;
#pragma unroll
        for (int r = 0; r < 4; ++r)
          MSc[(long)(mrow + r) * 256 + cm] = acc[mi][ni][r] + bv;
      }
    }
  }
}

// ---------------------------------------------------------------------------
// Flash attention, swapped-QK^T 32x32, KEY-SPLIT x2, FIXED-SHIFT softmax.
// (R9 version: mask staged one tile ahead into LDS via gl_lds4; VALU row-sum.)
__global__ __launch_bounds__(256, 4) void attn_fwd(
    const bf16* __restrict__ Q, const bf16* __restrict__ Km,
    const bf16* __restrict__ Vt, const float* __restrict__ M2,
    bf16* __restrict__ Opart, float* __restrict__ ml) {
  __shared__ bf16 lK[2][64 * 64];
  __shared__ bf16 lV[2][64 * 64];
  __shared__ alignas(16) float lM[2][64];
  const int tid = threadIdx.x, w = tid >> 6, l = tid & 63;
  const int q31 = l & 31, h32 = l >> 5;
  const int b = blockIdx.z >> 1, half = blockIdx.z & 1;
  const int hh = blockIdx.y, q0 = blockIdx.x * 128;
  const long S = 2048, H = 1024;
  const int kbase = half * 1024;

  bf16x8 qf[4];
  const long qrow = (long)b * S + q0 + w * 32 + q31;
#pragma unroll
  for (int sl = 0; sl < 4; ++sl)
    qf[sl] = *(const bf16x8*)(Q + qrow * H + hh * 64 + sl * 16 + h32 * 8);

  f32x16 o0 = {}, o1 = {};
  float lrun = 0.0f;

  const int swr = w * 16 + (l >> 3);
  const int swc = ((l & 7) ^ (l >> 3)) * 8;

  auto stage = [&](int p, int k0) {
#pragma unroll
    for (int j = 0; j < 2; ++j) {
      gl_lds16(Km + ((long)b * S + k0 + swr + 8 * j) * H + hh * 64 + swc,
               (char*)lK[p] + (w * 16 + 8 * j) * 128);
      gl_lds16(Vt + ((long)b * H + hh * 64 + swr + 8 * j) * S + k0 + swc,
               (char*)lV[p] + (w * 16 + 8 * j) * 128);
    }
    if (w == 0) gl_lds4(M2 + (long)b * S + k0 + l, (char*)lM[p]);
  };

  stage(0, kbase);
  __syncthreads();

  for (int t = 0; t < 16; ++t) {
    const int p = t & 1;
    if (t < 15) stage(p ^ 1, kbase + (t + 1) * 64);

    // init accumulators with shifted mask; reg r -> key (r&3)+8*(r>>2)+4*h32
    f32x16 s0, s1;
#pragma unroll
    for (int g = 0; g < 4; ++g) {
      const f32x4 m0 = *(const f32x4*)&lM[p][8 * g + 4 * h32];
      const f32x4 m1 = *(const f32x4*)&lM[p][32 + 8 * g + 4 * h32];
#pragma unroll
      for (int r = 0; r < 4; ++r) {
        s0[4 * g + r] = m0[r];
        s1[4 * g + r] = m1[r];
      }
    }

    // S = K Q^T (swapped); already exp2-scaled + shifted
    __builtin_amdgcn_s_setprio(1);
#pragma unroll
    for (int sl = 0; sl < 4; ++sl) {
      const int ch = sl * 2 + h32;
      const int cx = (ch ^ (q31 & 7)) * 16;
      const bf16x8 k0f = *(const bf16x8*)((const char*)lK[p] + q31 * 128 + cx);
      const bf16x8 k1f = *(const bf16x8*)((const char*)lK[p] + (32 + q31) * 128 + cx);
      s0 = MFMA32(k0f, qf[sl], s0);
      s1 = MFMA32(k1f, qf[sl], s1);
    }
    __builtin_amdgcn_s_setprio(0);

    // P = exp2(S) directly (fixed shift already applied)
#pragma unroll
    for (int i = 0; i < 16; ++i) s0[i] = __builtin_amdgcn_exp2f(s0[i]);
#pragma unroll
    for (int i = 0; i < 16; ++i) s1[i] = __builtin_amdgcn_exp2f(s1[i]);

    // row sum: in-lane tree + one cross-half shuffle
    f32x16 ts;
#pragma unroll
    for (int i = 0; i < 16; ++i) ts[i] = s0[i] + s1[i];
#pragma unroll
    for (int i = 0; i < 8; ++i) ts[i] += ts[i + 8];
#pragma unroll
    for (int i = 0; i < 4; ++i) ts[i] += ts[i + 4];
    float rs = (ts[0] + ts[1]) + (ts[2] + ts[3]);
    rs += __shfl_xor(rs, 32, 64);
    lrun += rs;

    // P -> PV A-frags: cvt_pk + permlane32_swap (T12)
    bf16x8 pa[4];
#pragma unroll
    for (int ks = 0; ks < 4; ++ks) {
      const int rb = (ks & 1) * 8;
      unsigned a0, a1, b0, b1;
      if (ks < 2) {
        a0 = cvtpk_bf16(s0[rb + 0], s0[rb + 1]);
        a1 = cvtpk_bf16(s0[rb + 2], s0[rb + 3]);
        b0 = cvtpk_bf16(s0[rb + 4], s0[rb + 5]);
        b1 = cvtpk_bf16(s0[rb + 6], s0[rb + 7]);
      } else {
        a0 = cvtpk_bf16(s1[rb + 0], s1[rb + 1]);
        a1 = cvtpk_bf16(s1[rb + 2], s1[rb + 3]);
        b0 = cvtpk_bf16(s1[rb + 4], s1[rb + 5]);
        b1 = cvtpk_bf16(s1[rb + 6], s1[rb + 7]);
      }
      const u32x2 r02 = __builtin_amdgcn_permlane32_swap(a0, b0, false, false);
      const u32x2 r13 = __builtin_amdgcn_permlane32_swap(a1, b1, false, false);
      const u32x4 pw = {r02[0], r13[0], r02[1], r13[1]};
      pa[ks] = __builtin_bit_cast(bf16x8, pw);
    }

    // O += P V
    __builtin_amdgcn_s_setprio(1);
#pragma unroll
    for (int ks = 0; ks < 4; ++ks) {
      const int ch = ks * 2 + h32;
      const int cx = (ch ^ (q31 & 7)) * 16;
      const bf16x8 v0 = *(const bf16x8*)((const char*)lV[p] + q31 * 128 + cx);
      const bf16x8 v1 = *(const bf16x8*)((const char*)lV[p] + (32 + q31) * 128 + cx);
      o0 = MFMA32(pa[ks], v0, o0);
      o1 = MFMA32(pa[ks], v1, o1);
    }
    __builtin_amdgcn_s_setprio(0);
    __syncthreads();
  }

  // epilogue: unnormalized O + l per (q,head,half)
  if (h32 == 0)
    ml[((long)half * 4096 + (long)b * 2048 + q0 + w * 32 + q31) * 16 + hh] = lrun;
#pragma unroll
  for (int reg = 0; reg < 16; ++reg) {
    const int row = (reg & 3) + 8 * (reg >> 2) + 4 * h32;
    const long qg = (long)b * 2048 + q0 + w * 32 + row;
    Opart[((long)half * 4096 + qg) * 1024 + hh * 64 + q31]      = (bf16)o0[reg];
    Opart[((long)half * 4096 + qg) * 1024 + hh * 64 + 32 + q31] = (bf16)o1[reg];
  }
}

// ---------------------------------------------------------------------------
extern "C" void kernel_launch(void* const* d_in, const int* in_sizes, int n_in,
                              void* d_out, int out_size, void* d_ws, size_t ws_size,
                              hipStream_t stream) {
  const float* X    = (const float*)d_in[0];
  const float* mask = (const float*)d_in[1];
  const float* Wq   = (const float*)d_in[2];  const float* bq  = (const float*)d_in[3];
  const float* Wk   = (const float*)d_in[4];  const float* bk  = (const float*)d_in[5];
  const float* Wv   = (const float*)d_in[6];  const float* bv  = (const float*)d_in[7];
  const float* Wo   = (const float*)d_in[8];  const float* bo  = (const float*)d_in[9];
  const float* mv   = (const float*)d_in[10];
  const float* Wmp  = (const float*)d_in[11]; const float* bmp = (const float*)d_in[12];
  const float* Wma  = (const float*)d_in[13]; const float* bma = (const float*)d_in[14];

  char* ws = (char*)d_ws;
  size_t off = 0;
  auto alloc = [&](size_t bytes) -> void* {
    void* p = ws + off;
    off += (bytes + 255) & ~(size_t)255;
    return p;
  };
  const long MS_ = 4096;
  bf16* Xb    = (bf16*)alloc(MS_ * 1024 * 2);
  bf16* Wqkvb = (bf16*)alloc(3328L * 1024 * 2);   // [Wq*QS | Wk | Wv | Wma]
  bf16* Wob   = (bf16*)alloc(1024 * 1024 * 2);
  bf16* Wmpb  = (bf16*)alloc(1024 * 512 * 2);
  bf16* mvTb  = (bf16*)alloc(512 * 256 * 2);
  float* M2   = (float*)alloc(MS_ * 4);
  float* bqkv = (float*)alloc(3328 * 4);
  bf16* Qb    = (bf16*)alloc(MS_ * 1024 * 2);
  bf16* Kb    = (bf16*)alloc(MS_ * 1024 * 2);
  bf16* Vtb   = (bf16*)alloc(MS_ * 1024 * 2);     // [B][h*64+d][S]
  bf16* Opart = (bf16*)alloc(2 * MS_ * 1024 * 2); // [2][4096][1024] = 16MB
  float* ml   = (float*)alloc(2 * MS_ * 16 * 4);  // [2][4096][16]
  float* MSc  = (float*)alloc(MS_ * 256 * 4);
  bf16* MP    = (bf16*)alloc(MS_ * 256 * 2);
  bf16* MO    = Kb;                               // dead after attn
  bf16* CB    = Qb;                               // dead after attn

  // 1: prep
  fused_prep<<<9480, 256, 0, stream>>>(X, Wq, Wk, Wv, Wo, Wma, Wmp, mask,
                                       bq, bk, bv, bma, mv,
                                       Xb, Wqkvb, Wob, Wmpb, M2, bqkv, mvTb);
  // 2: fused QKV + mem-score projection (XCD-swizzled flat grid, 4 blocks/CU)
  gemm_qkv<<<832, 256, 0, stream>>>(Xb, Wqkvb, bqkv, Qb, Kb, Vtb, MSc);
  // 3: attention, key-split x2 (combine deferred into gemm #5)
  attn_fwd<<<dim3(16, 16, 4), 256, 0, stream>>>(Qb, Kb, Vtb, M2, Opart, ml);
  // 4: mem-path softmax + probs @ mv^T
  softmax_rows256<<<1024, 256, 0, stream>>>(MSc, MP);
  gemm_bt<bf16, false><<<dim3(8, 32), 256, 0, stream>>>(MP, mvTb, nullptr, nullptr, nullptr,
                                                        MO, 4096, 512, 256, 1.0f);
  // 5: combined = 0.3*(mem_out @ Wmp^T + bmp) + combine(Opart, ml)
  gemm_bt<bf16, true><<<dim3(16, 32), 256, 0, stream>>>(MO, Wmpb, bmp, Opart, ml,
                                                        CB, 4096, 1024, 512, 0.3f);
  // 6: final projection -> fp32 out
  gemm_bt<float, false><<<dim3(16, 32), 256, 0, stream>>>(CB, Wob, bo, nullptr, nullptr,
                                                          (float*)d_out, 4096, 1024, 1024, 1.0f);
}

// Round 17
// 131.368 us; speedup vs baseline: 1.4221x; 1.0214x over previous
//
#include <hip/hip_runtime.h>

typedef __bf16 bf16;
typedef __bf16 bf16x8 __attribute__((ext_vector_type(8)));
typedef __bf16 bf16x4 __attribute__((ext_vector_type(4)));
typedef float  f32x4  __attribute__((ext_vector_type(4)));
typedef float  f32x16 __attribute__((ext_vector_type(16)));
typedef unsigned u32x2 __attribute__((ext_vector_type(2)));
typedef unsigned u32x4 __attribute__((ext_vector_type(4)));
typedef unsigned long long uptr;

#define MFMA16(a, b, c) __builtin_amdgcn_mfma_f32_16x16x32_bf16((a), (b), (c), 0, 0, 0)
#define MFMA32(a, b, c) __builtin_amdgcn_mfma_f32_32x32x16_bf16((a), (b), (c), 0, 0, 0)

__device__ __forceinline__ void gl_lds16(const void* g, void* l) {
  __builtin_amdgcn_global_load_lds(
      (__attribute__((address_space(1))) void*)(uptr)(g),
      (__attribute__((address_space(3))) void*)(uptr)(l),
      16, 0, 0);
}
__device__ __forceinline__ void gl_lds4(const void* g, void* l) {
  __builtin_amdgcn_global_load_lds(
      (__attribute__((address_space(1))) void*)(uptr)(g),
      (__attribute__((address_space(3))) void*)(uptr)(l),
      4, 0, 0);
}
__device__ __forceinline__ unsigned cvtpk_bf16(float lo, float hi) {
  unsigned r;
  asm("v_cvt_pk_bf16_f32 %0, %1, %2" : "=v"(r) : "v"(lo), "v"(hi));
  return r;
}

// ---------------------------------------------------------------------------
// Fused prep. Wq/bq PRE-SCALED by 0.125*log2(e). Wma appended to Wqkvb
// (rows 3072..3327) and bma to bqkv. M2 = mask*(-1e9*log2e) - 40 (fixed shift).
// mv converted to bf16 (row-major; used as B-operand of the Wfold GEMM).
__global__ __launch_bounds__(256) void fused_prep(
    const float* __restrict__ X, const float* __restrict__ Wq,
    const float* __restrict__ Wk, const float* __restrict__ Wv,
    const float* __restrict__ Wo, const float* __restrict__ Wma,
    const float* __restrict__ Wmp, const float* __restrict__ mask,
    const float* __restrict__ bq, const float* __restrict__ bk,
    const float* __restrict__ bv, const float* __restrict__ bma,
    const float* __restrict__ mv,
    bf16* __restrict__ Xb, bf16* __restrict__ Wqkvb, bf16* __restrict__ Wob,
    bf16* __restrict__ Wmpb,
    float* __restrict__ M2, float* __restrict__ bqkv, bf16* __restrict__ mvb) {
  const int bid = blockIdx.x, t = threadIdx.x;
  const float QS = 0.125f * 1.44269504f;
  auto cvt = [&](const float* src, bf16* dst, int blk, float sc) {
    const long i = ((long)blk * 256 + t) * 4;
    const float4 v = *(const float4*)(src + i);
    bf16x4 o = {(bf16)(v.x * sc), (bf16)(v.y * sc), (bf16)(v.z * sc), (bf16)(v.w * sc)};
    *(bf16x4*)(dst + i) = o;
  };
  if (bid < 4096) cvt(X, Xb, bid, 1.0f);
  else if (bid < 5120) cvt(Wq, Wqkvb, bid - 4096, QS);
  else if (bid < 6144) cvt(Wk, Wqkvb + 1024 * 1024, bid - 5120, 1.0f);
  else if (bid < 7168) cvt(Wv, Wqkvb + 2 * 1024 * 1024, bid - 6144, 1.0f);
  else if (bid < 8192) cvt(Wo, Wob, bid - 7168, 1.0f);
  else if (bid < 8448) cvt(Wma, Wqkvb + 3072 * 1024, bid - 8192, 1.0f);
  else if (bid < 8960) cvt(Wmp, Wmpb, bid - 8448, 1.0f);
  else if (bid < 8964) {
    const long i = ((long)(bid - 8960) * 256 + t) * 4;
    const float4 v = *(const float4*)(mask + i);
    float4 o = {v.x * -1.44269504e9f - 40.0f, v.y * -1.44269504e9f - 40.0f,
                v.z * -1.44269504e9f - 40.0f, v.w * -1.44269504e9f - 40.0f};
    *(float4*)(M2 + i) = o;
  } else if (bid < 8967) {
    const int s = bid - 8964;
    const float* src = s == 0 ? bq : (s == 1 ? bk : bv);
    const float sc = s == 0 ? QS : 1.0f;
    float4 v = *(const float4*)(src + t * 4);
    float4 o = {v.x * sc, v.y * sc, v.z * sc, v.w * sc};
    *(float4*)(bqkv + s * 1024 + t * 4) = o;
  } else if (bid < 8968) {
    if (t < 64) *(float4*)(bqkv + 3072 + t * 4) = *(const float4*)(bma + t * 4);
  } else {  // mv [256][512] fp32 -> bf16 (128 blocks)
    cvt(mv, mvb, bid - 8968, 1.0f);
  }
}

// row softmax over 256 cols, fp32 in, bf16 out. one wave per row.
__global__ __launch_bounds__(256) void softmax_rows256(const float* __restrict__ in,
                                                       bf16* __restrict__ out) {
  const int w = threadIdx.x >> 6, l = threadIdx.x & 63;
  const long row = (long)blockIdx.x * 4 + w;
  const float4 v = *(const float4*)(in + row * 256 + l * 4);
  float mx = fmaxf(fmaxf(v.x, v.y), fmaxf(v.z, v.w));
  mx = fmaxf(mx, __shfl_xor(mx, 1, 64));
  mx = fmaxf(mx, __shfl_xor(mx, 2, 64));
  mx = fmaxf(mx, __shfl_xor(mx, 4, 64));
  mx = fmaxf(mx, __shfl_xor(mx, 8, 64));
  mx = fmaxf(mx, __shfl_xor(mx, 16, 64));
  mx = fmaxf(mx, __shfl_xor(mx, 32, 64));
  const float e0 = __expf(v.x - mx), e1 = __expf(v.y - mx);
  const float e2 = __expf(v.z - mx), e3 = __expf(v.w - mx);
  float sm = e0 + e1 + e2 + e3;
  sm += __shfl_xor(sm, 1, 64);
  sm += __shfl_xor(sm, 2, 64);
  sm += __shfl_xor(sm, 4, 64);
  sm += __shfl_xor(sm, 8, 64);
  sm += __shfl_xor(sm, 16, 64);
  sm += __shfl_xor(sm, 32, 64);
  const float inv = 1.0f / sm;
  bf16x4 o = {(bf16)(e0 * inv), (bf16)(e1 * inv), (bf16)(e2 * inv), (bf16)(e3 * inv)};
  *(bf16x4*)(out + row * 256 + l * 4) = o;
}

// ---------------------------------------------------------------------------
// Generic GEMM: C[M][N] = (A[M][K] @ B[N][K]^T + bias)*alpha (+ combine-add)
// COMBINE: attention key-half merge fused into the epilogue; h = n0>>6 is
// block-uniform so the l0/l1 loads + reciprocal hoist out of the loops.
template <typename OutT, bool COMBINE>
__global__ __launch_bounds__(256, 3) void gemm_bt(
    const bf16* __restrict__ A, const bf16* __restrict__ B,
    const float* __restrict__ bias, const bf16* __restrict__ Op,
    const float* __restrict__ mlp, OutT* __restrict__ C,
    int M, int N, int K, float alpha) {
  __shared__ bf16 lA[2][128 * 64];
  __shared__ bf16 lB[2][64 * 64];
  const int tid = threadIdx.x;
  const int w = tid >> 6, l = tid & 63;
  const int hi = l >> 4, lo = l & 15;
  const int m0 = blockIdx.y * 128, n0 = blockIdx.x * 64;
  const int wm = w * 32;

  const int sr8 = l >> 3;
  const int sc = (l & 7) * 8;
  const long aRow = (long)(m0 + wm + sr8);
  const long bRow = (long)(n0 + w * 16 + sr8);

  auto stage = [&](int p, int k0) {
#pragma unroll
    for (int j = 0; j < 4; ++j)
      gl_lds16(A + (aRow + 8 * j) * K + k0 + sc, (char*)lA[p] + (wm + 8 * j) * 128);
#pragma unroll
    for (int j = 0; j < 2; ++j)
      gl_lds16(B + (bRow + 8 * j) * K + k0 + sc, (char*)lB[p] + (w * 16 + 8 * j) * 128);
  };

  f32x4 acc[2][4] = {};
  stage(0, 0);
  __syncthreads();
  const int nt = K >> 6;

  for (int t = 0; t < nt; ++t) {
    const int p = t & 1;
    if (t + 1 < nt) stage(p ^ 1, (t + 1) << 6);
#pragma unroll
    for (int kk = 0; kk < 2; ++kk) {
      bf16x8 af[2], bfr[4];
#pragma unroll
      for (int mi = 0; mi < 2; ++mi)
        af[mi] = *(const bf16x8*)((const char*)lA[p] + (wm + mi * 16 + lo) * 128 + kk * 64 + hi * 16);
#pragma unroll
      for (int ni = 0; ni < 4; ++ni)
        bfr[ni] = *(const bf16x8*)((const char*)lB[p] + (ni * 16 + lo) * 128 + kk * 64 + hi * 16);
      __builtin_amdgcn_s_setprio(1);
#pragma unroll
      for (int mi = 0; mi < 2; ++mi)
#pragma unroll
        for (int ni = 0; ni < 4; ++ni)
          acc[mi][ni] = MFMA16(af[mi], bfr[ni], acc[mi][ni]);
      __builtin_amdgcn_s_setprio(0);
    }
    __syncthreads();
  }

  // COMBINE: per-row normalization factor, hoisted (h is block-uniform)
  float cinv[2][4];
  if (COMBINE) {
    const int h = n0 >> 6;
#pragma unroll
    for (int mi = 0; mi < 2; ++mi)
#pragma unroll
      for (int r = 0; r < 4; ++r) {
        const long row = m0 + wm + mi * 16 + hi * 4 + r;
        cinv[mi][r] = 1.0f / (mlp[row * 16 + h] + mlp[(4096L + row) * 16 + h]);
      }
  }

#pragma unroll
  for (int ni = 0; ni < 4; ++ni) {
    const int col = n0 + ni * 16 + lo;
    const float bv = bias ? bias[col] : 0.0f;
#pragma unroll
    for (int mi = 0; mi < 2; ++mi) {
      const int mrow = m0 + wm + mi * 16 + hi * 4;
#pragma unroll
      for (int r = 0; r < 4; ++r) {
        const long row = mrow + r;
        float v = (acc[mi][ni][r] + bv) * alpha;
        if (COMBINE) {
          const float o0v = (float)Op[row * 1024 + col];
          const float o1v = (float)Op[4096L * 1024 + row * 1024 + col];
          v += (o0v + o1v) * cinv[mi][r];
        }
        C[row * (long)N + col] = (OutT)v;
      }
    }
  }
}

// Fused QKV + mem-score projection, m97 128x128 structure, 4 blocks/CU,
// XCD-swizzled flat grid (832 = 8 XCD x 104; consecutive roles share B-panel).
__global__ __launch_bounds__(256, 4) void gemm_qkv(
    const bf16* __restrict__ A, const bf16* __restrict__ B,
    const float* __restrict__ bias, bf16* __restrict__ Qo,
    bf16* __restrict__ Ko, bf16* __restrict__ Vto, float* __restrict__ MSc) {
  const int K = 1024;
  __shared__ bf16 smem[2][128 * 64];   // lA | lB; reused as transpose buf
  bf16* lA = smem[0];
  bf16* lB = smem[1];
  const int lin = blockIdx.x;
  const int role = (lin & 7) * 104 + (lin >> 3);   // 832/8 = 104 per XCD
  const int m0 = (role & 31) * 128;                // m fastest within XCD
  const int n0 = (role >> 5) * 128;
  const int tid = threadIdx.x;
  const int w = tid >> 6, l = tid & 63;
  const int hi = l >> 4, lo = l & 15;
  const int wm = (w >> 1) * 64, wn = (w & 1) * 64;

  const int sr = w * 32 + (l >> 3);
  const int sc = (l & 7) * 8;
  const long aBase = (long)(m0 + sr) * K + sc;
  const long bBase = (long)(n0 + sr) * K + sc;

  f32x4 acc[4][4] = {};

  for (int k0 = 0; k0 < K; k0 += 64) {
#pragma unroll
    for (int j = 0; j < 4; ++j) {
      gl_lds16(A + aBase + (long)8 * j * K + k0, (char*)lA + (w * 32 + 8 * j) * 128);
      gl_lds16(B + bBase + (long)8 * j * K + k0, (char*)lB + (w * 32 + 8 * j) * 128);
    }
    __syncthreads();
#pragma unroll
    for (int kk = 0; kk < 2; ++kk) {
      bf16x8 af[4], bfr[4];
#pragma unroll
      for (int i = 0; i < 4; ++i) {
        af[i]  = *(const bf16x8*)((const char*)lA + (wm + i * 16 + lo) * 128 + kk * 64 + hi * 16);
        bfr[i] = *(const bf16x8*)((const char*)lB + (wn + i * 16 + lo) * 128 + kk * 64 + hi * 16);
      }
#pragma unroll
      for (int mi = 0; mi < 4; ++mi)
#pragma unroll
        for (int ni = 0; ni < 4; ++ni)
          acc[mi][ni] = MFMA16(af[mi], bfr[ni], acc[mi][ni]);
    }
    __syncthreads();
  }

  if (n0 < 2048) {       // Q or K
#pragma unroll
    for (int ni = 0; ni < 4; ++ni) {
      const int col = n0 + wn + ni * 16 + lo;
      const float bv = bias[col];
#pragma unroll
      for (int mi = 0; mi < 4; ++mi) {
        const int mrow = m0 + wm + mi * 16 + hi * 4;
#pragma unroll
        for (int r = 0; r < 4; ++r) {
          const long row = mrow + r;
          const float v = acc[mi][ni][r] + bv;
          if (n0 < 1024) Qo[row * 1024 + col] = (bf16)v;
          else           Ko[row * 1024 + (col - 1024)] = (bf16)v;
        }
      }
    }
  } else if (n0 < 3072) {  // V: transpose through LDS, coalesced Vt writes
    bf16* sT = smem[0];
#pragma unroll
    for (int ni = 0; ni < 4; ++ni) {
      const int cT = wn + ni * 16 + lo;
      const float bv = bias[n0 + cT];
#pragma unroll
      for (int mi = 0; mi < 4; ++mi) {
        const int rT = wm + mi * 16 + hi * 4;
        u32x2 pw = {cvtpk_bf16(acc[mi][ni][0] + bv, acc[mi][ni][1] + bv),
                    cvtpk_bf16(acc[mi][ni][2] + bv, acc[mi][ni][3] + bv)};
        *(u32x2*)((char*)sT + cT * 256 + ((rT * 2) ^ ((cT & 15) << 3))) = pw;
      }
    }
    __syncthreads();
    const long vrow0 = (long)(m0 >> 11) * 1024 + (n0 - 2048);
    const int srow = m0 & 2047;
#pragma unroll
    for (int dd = 0; dd < 32; ++dd) {
      const int d = w * 32 + dd;
      const unsigned pv = *(const unsigned*)((const char*)sT + d * 256 + ((l * 4) ^ ((d & 15) << 3)));
      *(unsigned*)((char*)(Vto + (vrow0 + d) * 2048 + srow) + l * 4) = pv;
    }
  } else {               // mem-scores -> MSc fp32 [4096][256]
#pragma unroll
    for (int ni = 0; ni < 4; ++ni) {
      const int col = n0 + wn + ni * 16 + lo;
      const float bv = bias[col];
      const int cm = col - 3072;
#pragma unroll
      for (int mi = 0; mi < 4; ++mi) {
        const int mrow = m0 + wm + mi * 16 + hi * 4;
#pragma unroll
        for (int r = 0; r < 4; ++r)
          MSc[(long)(mrow + r) * 256 + cm] = acc[mi][ni][r] + bv;
      }
    }
  }
}

// ---------------------------------------------------------------------------
// Flash attention, swapped-QK^T 32x32, KEY-SPLIT x2, FIXED-SHIFT softmax.
__global__ __launch_bounds__(256, 4) void attn_fwd(
    const bf16* __restrict__ Q, const bf16* __restrict__ Km,
    const bf16* __restrict__ Vt, const float* __restrict__ M2,
    bf16* __restrict__ Opart, float* __restrict__ ml) {
  __shared__ bf16 lK[2][64 * 64];
  __shared__ bf16 lV[2][64 * 64];
  __shared__ alignas(16) float lM[2][64];
  const int tid = threadIdx.x, w = tid >> 6, l = tid & 63;
  const int q31 = l & 31, h32 = l >> 5;
  const int b = blockIdx.z >> 1, half = blockIdx.z & 1;
  const int hh = blockIdx.y, q0 = blockIdx.x * 128;
  const long S = 2048, H = 1024;
  const int kbase = half * 1024;

  bf16x8 qf[4];
  const long qrow = (long)b * S + q0 + w * 32 + q31;
#pragma unroll
  for (int sl = 0; sl < 4; ++sl)
    qf[sl] = *(const bf16x8*)(Q + qrow * H + hh * 64 + sl * 16 + h32 * 8);

  f32x16 o0 = {}, o1 = {};
  float lrun = 0.0f;

  const int swr = w * 16 + (l >> 3);
  const int swc = ((l & 7) ^ (l >> 3)) * 8;

  auto stage = [&](int p, int k0) {
#pragma unroll
    for (int j = 0; j < 2; ++j) {
      gl_lds16(Km + ((long)b * S + k0 + swr + 8 * j) * H + hh * 64 + swc,
               (char*)lK[p] + (w * 16 + 8 * j) * 128);
      gl_lds16(Vt + ((long)b * H + hh * 64 + swr + 8 * j) * S + k0 + swc,
               (char*)lV[p] + (w * 16 + 8 * j) * 128);
    }
    if (w == 0) gl_lds4(M2 + (long)b * S + k0 + l, (char*)lM[p]);
  };

  stage(0, kbase);
  __syncthreads();

  for (int t = 0; t < 16; ++t) {
    const int p = t & 1;
    if (t < 15) stage(p ^ 1, kbase + (t + 1) * 64);

    // init accumulators with shifted mask; reg r -> key (r&3)+8*(r>>2)+4*h32
    f32x16 s0, s1;
#pragma unroll
    for (int g = 0; g < 4; ++g) {
      const f32x4 m0 = *(const f32x4*)&lM[p][8 * g + 4 * h32];
      const f32x4 m1 = *(const f32x4*)&lM[p][32 + 8 * g + 4 * h32];
#pragma unroll
      for (int r = 0; r < 4; ++r) {
        s0[4 * g + r] = m0[r];
        s1[4 * g + r] = m1[r];
      }
    }

    // S = K Q^T (swapped); already exp2-scaled + shifted
    __builtin_amdgcn_s_setprio(1);
#pragma unroll
    for (int sl = 0; sl < 4; ++sl) {
      const int ch = sl * 2 + h32;
      const int cx = (ch ^ (q31 & 7)) * 16;
      const bf16x8 k0f = *(const bf16x8*)((const char*)lK[p] + q31 * 128 + cx);
      const bf16x8 k1f = *(const bf16x8*)((const char*)lK[p] + (32 + q31) * 128 + cx);
      s0 = MFMA32(k0f, qf[sl], s0);
      s1 = MFMA32(k1f, qf[sl], s1);
    }
    __builtin_amdgcn_s_setprio(0);

    // P = exp2(S) directly (fixed shift already applied)
#pragma unroll
    for (int i = 0; i < 16; ++i) s0[i] = __builtin_amdgcn_exp2f(s0[i]);
#pragma unroll
    for (int i = 0; i < 16; ++i) s1[i] = __builtin_amdgcn_exp2f(s1[i]);

    // row sum: in-lane tree + one cross-half shuffle
    f32x16 ts;
#pragma unroll
    for (int i = 0; i < 16; ++i) ts[i] = s0[i] + s1[i];
#pragma unroll
    for (int i = 0; i < 8; ++i) ts[i] += ts[i + 8];
#pragma unroll
    for (int i = 0; i < 4; ++i) ts[i] += ts[i + 4];
    float rs = (ts[0] + ts[1]) + (ts[2] + ts[3]);
    rs += __shfl_xor(rs, 32, 64);
    lrun += rs;

    // P -> PV A-frags: cvt_pk + permlane32_swap (T12)
    bf16x8 pa[4];
#pragma unroll
    for (int ks = 0; ks < 4; ++ks) {
      const int rb = (ks & 1) * 8;
      unsigned a0, a1, b0, b1;
      if (ks < 2) {
        a0 = cvtpk_bf16(s0[rb + 0], s0[rb + 1]);
        a1 = cvtpk_bf16(s0[rb + 2], s0[rb + 3]);
        b0 = cvtpk_bf16(s0[rb + 4], s0[rb + 5]);
        b1 = cvtpk_bf16(s0[rb + 6], s0[rb + 7]);
      } else {
        a0 = cvtpk_bf16(s1[rb + 0], s1[rb + 1]);
        a1 = cvtpk_bf16(s1[rb + 2], s1[rb + 3]);
        b0 = cvtpk_bf16(s1[rb + 4], s1[rb + 5]);
        b1 = cvtpk_bf16(s1[rb + 6], s1[rb + 7]);
      }
      const u32x2 r02 = __builtin_amdgcn_permlane32_swap(a0, b0, false, false);
      const u32x2 r13 = __builtin_amdgcn_permlane32_swap(a1, b1, false, false);
      const u32x4 pw = {r02[0], r13[0], r02[1], r13[1]};
      pa[ks] = __builtin_bit_cast(bf16x8, pw);
    }

    // O += P V
    __builtin_amdgcn_s_setprio(1);
#pragma unroll
    for (int ks = 0; ks < 4; ++ks) {
      const int ch = ks * 2 + h32;
      const int cx = (ch ^ (q31 & 7)) * 16;
      const bf16x8 v0 = *(const bf16x8*)((const char*)lV[p] + q31 * 128 + cx);
      const bf16x8 v1 = *(const bf16x8*)((const char*)lV[p] + (32 + q31) * 128 + cx);
      o0 = MFMA32(pa[ks], v0, o0);
      o1 = MFMA32(pa[ks], v1, o1);
    }
    __builtin_amdgcn_s_setprio(0);
    __syncthreads();
  }

  // epilogue: unnormalized O + l per (q,head,half)
  if (h32 == 0)
    ml[((long)half * 4096 + (long)b * 2048 + q0 + w * 32 + q31) * 16 + hh] = lrun;
#pragma unroll
  for (int reg = 0; reg < 16; ++reg) {
    const int row = (reg & 3) + 8 * (reg >> 2) + 4 * h32;
    const long qg = (long)b * 2048 + q0 + w * 32 + row;
    Opart[((long)half * 4096 + qg) * 1024 + hh * 64 + q31]      = (bf16)o0[reg];
    Opart[((long)half * 4096 + qg) * 1024 + hh * 64 + 32 + q31] = (bf16)o1[reg];
  }
}

// ---------------------------------------------------------------------------
extern "C" void kernel_launch(void* const* d_in, const int* in_sizes, int n_in,
                              void* d_out, int out_size, void* d_ws, size_t ws_size,
                              hipStream_t stream) {
  const float* X    = (const float*)d_in[0];
  const float* mask = (const float*)d_in[1];
  const float* Wq   = (const float*)d_in[2];  const float* bq  = (const float*)d_in[3];
  const float* Wk   = (const float*)d_in[4];  const float* bk  = (const float*)d_in[5];
  const float* Wv   = (const float*)d_in[6];  const float* bv  = (const float*)d_in[7];
  const float* Wo   = (const float*)d_in[8];  const float* bo  = (const float*)d_in[9];
  const float* mv   = (const float*)d_in[10];
  const float* Wmp  = (const float*)d_in[11]; const float* bmp = (const float*)d_in[12];
  const float* Wma  = (const float*)d_in[13]; const float* bma = (const float*)d_in[14];

  char* ws = (char*)d_ws;
  size_t off = 0;
  auto alloc = [&](size_t bytes) -> void* {
    void* p = ws + off;
    off += (bytes + 255) & ~(size_t)255;
    return p;
  };
  const long MS_ = 4096;
  bf16* Xb    = (bf16*)alloc(MS_ * 1024 * 2);
  bf16* Wqkvb = (bf16*)alloc(3328L * 1024 * 2);   // [Wq*QS | Wk | Wv | Wma]
  bf16* Wob   = (bf16*)alloc(1024 * 1024 * 2);
  bf16* Wmpb  = (bf16*)alloc(1024 * 512 * 2);
  bf16* mvb   = (bf16*)alloc(256 * 512 * 2);
  bf16* WfoldT= (bf16*)alloc(1024 * 256 * 2);     // Wmp @ mv^T
  float* M2   = (float*)alloc(MS_ * 4);
  float* bqkv = (float*)alloc(3328 * 4);
  bf16* Qb    = (bf16*)alloc(MS_ * 1024 * 2);
  bf16* Kb    = (bf16*)alloc(MS_ * 1024 * 2);
  bf16* Vtb   = (bf16*)alloc(MS_ * 1024 * 2);     // [B][h*64+d][S]
  bf16* Opart = (bf16*)alloc(2 * MS_ * 1024 * 2); // [2][4096][1024] = 16MB
  float* ml   = (float*)alloc(2 * MS_ * 16 * 4);  // [2][4096][16]
  float* MSc  = (float*)alloc(MS_ * 256 * 4);
  bf16* MP    = (bf16*)alloc(MS_ * 256 * 2);
  bf16* CB    = Qb;                               // dead after attn

  // 1: prep
  fused_prep<<<9096, 256, 0, stream>>>(X, Wq, Wk, Wv, Wo, Wma, Wmp, mask,
                                       bq, bk, bv, bma, mv,
                                       Xb, Wqkvb, Wob, Wmpb, M2, bqkv, mvb);
  // 2: WfoldT = Wmp @ mv^T  [1024][256]  (folds memory_values into Wmp)
  gemm_bt<bf16, false><<<dim3(4, 8), 256, 0, stream>>>(Wmpb, mvb, nullptr, nullptr, nullptr,
                                                       WfoldT, 1024, 256, 512, 1.0f);
  // 3: fused QKV + mem-score projection (XCD-swizzled flat grid, 4 blocks/CU)
  gemm_qkv<<<832, 256, 0, stream>>>(Xb, Wqkvb, bqkv, Qb, Kb, Vtb, MSc);
  // 4: attention, key-split x2 (combine deferred into gemm #6)
  attn_fwd<<<dim3(16, 16, 4), 256, 0, stream>>>(Qb, Kb, Vtb, M2, Opart, ml);
  // 5: mem-path softmax
  softmax_rows256<<<1024, 256, 0, stream>>>(MSc, MP);
  // 6: combined = 0.3*(probs @ WfoldT^T + bmp) + combine(Opart, ml)
  //    (identity: probs@(Wmp@mv^T)^T = (probs@mv)@Wmp^T)
  gemm_bt<bf16, true><<<dim3(16, 32), 256, 0, stream>>>(MP, WfoldT, bmp, Opart, ml,
                                                        CB, 4096, 1024, 256, 0.3f);
  // 7: final projection -> fp32 out
  gemm_bt<float, false><<<dim3(16, 32), 256, 0, stream>>>(CB, Wob, bo, nullptr, nullptr,
                                                          (float*)d_out, 4096, 1024, 1024, 1.0f);
}

// Round 18
// 131.017 us; speedup vs baseline: 1.4259x; 1.0027x over previous
//
#include <hip/hip_runtime.h>

typedef __bf16 bf16;
typedef __bf16 bf16x8 __attribute__((ext_vector_type(8)));
typedef __bf16 bf16x4 __attribute__((ext_vector_type(4)));
typedef float  f32x4  __attribute__((ext_vector_type(4)));
typedef float  f32x16 __attribute__((ext_vector_type(16)));
typedef unsigned u32x2 __attribute__((ext_vector_type(2)));
typedef unsigned u32x4 __attribute__((ext_vector_type(4)));
typedef unsigned long long uptr;

#define MFMA16(a, b, c) __builtin_amdgcn_mfma_f32_16x16x32_bf16((a), (b), (c), 0, 0, 0)
#define MFMA32(a, b, c) __builtin_amdgcn_mfma_f32_32x32x16_bf16((a), (b), (c), 0, 0, 0)

__device__ __forceinline__ void gl_lds16(const void* g, void* l) {
  __builtin_amdgcn_global_load_lds(
      (__attribute__((address_space(1))) void*)(uptr)(g),
      (__attribute__((address_space(3))) void*)(uptr)(l),
      16, 0, 0);
}
__device__ __forceinline__ void gl_lds4(const void* g, void* l) {
  __builtin_amdgcn_global_load_lds(
      (__attribute__((address_space(1))) void*)(uptr)(g),
      (__attribute__((address_space(3))) void*)(uptr)(l),
      4, 0, 0);
}
__device__ __forceinline__ unsigned cvtpk_bf16(float lo, float hi) {
  unsigned r;
  asm("v_cvt_pk_bf16_f32 %0, %1, %2" : "=v"(r) : "v"(lo), "v"(hi));
  return r;
}

// ---------------------------------------------------------------------------
// Fused prep. Wq/bq PRE-SCALED by 0.125*log2(e). Wma appended to Wqkvb
// (rows 3072..3327) and bma to bqkv. M2 = mask*(-1e9*log2e) - 40 (fixed shift).
// mv converted to bf16 (row-major; used as B-operand of the Wfold GEMM).
__global__ __launch_bounds__(256) void fused_prep(
    const float* __restrict__ X, const float* __restrict__ Wq,
    const float* __restrict__ Wk, const float* __restrict__ Wv,
    const float* __restrict__ Wo, const float* __restrict__ Wma,
    const float* __restrict__ Wmp, const float* __restrict__ mask,
    const float* __restrict__ bq, const float* __restrict__ bk,
    const float* __restrict__ bv, const float* __restrict__ bma,
    const float* __restrict__ mv,
    bf16* __restrict__ Xb, bf16* __restrict__ Wqkvb, bf16* __restrict__ Wob,
    bf16* __restrict__ Wmpb,
    float* __restrict__ M2, float* __restrict__ bqkv, bf16* __restrict__ mvb) {
  const int bid = blockIdx.x, t = threadIdx.x;
  const float QS = 0.125f * 1.44269504f;
  auto cvt = [&](const float* src, bf16* dst, int blk, float sc) {
    const long i = ((long)blk * 256 + t) * 4;
    const float4 v = *(const float4*)(src + i);
    bf16x4 o = {(bf16)(v.x * sc), (bf16)(v.y * sc), (bf16)(v.z * sc), (bf16)(v.w * sc)};
    *(bf16x4*)(dst + i) = o;
  };
  if (bid < 4096) cvt(X, Xb, bid, 1.0f);
  else if (bid < 5120) cvt(Wq, Wqkvb, bid - 4096, QS);
  else if (bid < 6144) cvt(Wk, Wqkvb + 1024 * 1024, bid - 5120, 1.0f);
  else if (bid < 7168) cvt(Wv, Wqkvb + 2 * 1024 * 1024, bid - 6144, 1.0f);
  else if (bid < 8192) cvt(Wo, Wob, bid - 7168, 1.0f);
  else if (bid < 8448) cvt(Wma, Wqkvb + 3072 * 1024, bid - 8192, 1.0f);
  else if (bid < 8960) cvt(Wmp, Wmpb, bid - 8448, 1.0f);
  else if (bid < 8964) {
    const long i = ((long)(bid - 8960) * 256 + t) * 4;
    const float4 v = *(const float4*)(mask + i);
    float4 o = {v.x * -1.44269504e9f - 40.0f, v.y * -1.44269504e9f - 40.0f,
                v.z * -1.44269504e9f - 40.0f, v.w * -1.44269504e9f - 40.0f};
    *(float4*)(M2 + i) = o;
  } else if (bid < 8967) {
    const int s = bid - 8964;
    const float* src = s == 0 ? bq : (s == 1 ? bk : bv);
    const float sc = s == 0 ? QS : 1.0f;
    float4 v = *(const float4*)(src + t * 4);
    float4 o = {v.x * sc, v.y * sc, v.z * sc, v.w * sc};
    *(float4*)(bqkv + s * 1024 + t * 4) = o;
  } else if (bid < 8968) {
    if (t < 64) *(float4*)(bqkv + 3072 + t * 4) = *(const float4*)(bma + t * 4);
  } else {  // mv [256][512] fp32 -> bf16 (128 blocks)
    cvt(mv, mvb, bid - 8968, 1.0f);
  }
}

// row softmax over 256 cols, fp32 in, bf16 out. one wave per row.
__global__ __launch_bounds__(256) void softmax_rows256(const float* __restrict__ in,
                                                       bf16* __restrict__ out) {
  const int w = threadIdx.x >> 6, l = threadIdx.x & 63;
  const long row = (long)blockIdx.x * 4 + w;
  const float4 v = *(const float4*)(in + row * 256 + l * 4);
  float mx = fmaxf(fmaxf(v.x, v.y), fmaxf(v.z, v.w));
  mx = fmaxf(mx, __shfl_xor(mx, 1, 64));
  mx = fmaxf(mx, __shfl_xor(mx, 2, 64));
  mx = fmaxf(mx, __shfl_xor(mx, 4, 64));
  mx = fmaxf(mx, __shfl_xor(mx, 8, 64));
  mx = fmaxf(mx, __shfl_xor(mx, 16, 64));
  mx = fmaxf(mx, __shfl_xor(mx, 32, 64));
  const float e0 = __expf(v.x - mx), e1 = __expf(v.y - mx);
  const float e2 = __expf(v.z - mx), e3 = __expf(v.w - mx);
  float sm = e0 + e1 + e2 + e3;
  sm += __shfl_xor(sm, 1, 64);
  sm += __shfl_xor(sm, 2, 64);
  sm += __shfl_xor(sm, 4, 64);
  sm += __shfl_xor(sm, 8, 64);
  sm += __shfl_xor(sm, 16, 64);
  sm += __shfl_xor(sm, 32, 64);
  const float inv = 1.0f / sm;
  bf16x4 o = {(bf16)(e0 * inv), (bf16)(e1 * inv), (bf16)(e2 * inv), (bf16)(e3 * inv)};
  *(bf16x4*)(out + row * 256 + l * 4) = o;
}

// ---------------------------------------------------------------------------
// Generic GEMM: C[M][N] = (A[M][K] @ B[N][K]^T + bias)*alpha (+ combine-add)
// COMBINE: attention key-half merge fused into the epilogue; h = n0>>6 is
// block-uniform so the l0/l1 loads + reciprocal hoist out of the loops.
template <typename OutT, bool COMBINE>
__global__ __launch_bounds__(256, 3) void gemm_bt(
    const bf16* __restrict__ A, const bf16* __restrict__ B,
    const float* __restrict__ bias, const bf16* __restrict__ Op,
    const float* __restrict__ mlp, OutT* __restrict__ C,
    int M, int N, int K, float alpha) {
  __shared__ bf16 lA[2][128 * 64];
  __shared__ bf16 lB[2][64 * 64];
  const int tid = threadIdx.x;
  const int w = tid >> 6, l = tid & 63;
  const int hi = l >> 4, lo = l & 15;
  const int m0 = blockIdx.y * 128, n0 = blockIdx.x * 64;
  const int wm = w * 32;

  const int sr8 = l >> 3;
  const int sc = (l & 7) * 8;
  const long aRow = (long)(m0 + wm + sr8);
  const long bRow = (long)(n0 + w * 16 + sr8);

  auto stage = [&](int p, int k0) {
#pragma unroll
    for (int j = 0; j < 4; ++j)
      gl_lds16(A + (aRow + 8 * j) * K + k0 + sc, (char*)lA[p] + (wm + 8 * j) * 128);
#pragma unroll
    for (int j = 0; j < 2; ++j)
      gl_lds16(B + (bRow + 8 * j) * K + k0 + sc, (char*)lB[p] + (w * 16 + 8 * j) * 128);
  };

  f32x4 acc[2][4] = {};
  stage(0, 0);
  __syncthreads();
  const int nt = K >> 6;

  for (int t = 0; t < nt; ++t) {
    const int p = t & 1;
    if (t + 1 < nt) stage(p ^ 1, (t + 1) << 6);
#pragma unroll
    for (int kk = 0; kk < 2; ++kk) {
      bf16x8 af[2], bfr[4];
#pragma unroll
      for (int mi = 0; mi < 2; ++mi)
        af[mi] = *(const bf16x8*)((const char*)lA[p] + (wm + mi * 16 + lo) * 128 + kk * 64 + hi * 16);
#pragma unroll
      for (int ni = 0; ni < 4; ++ni)
        bfr[ni] = *(const bf16x8*)((const char*)lB[p] + (ni * 16 + lo) * 128 + kk * 64 + hi * 16);
      __builtin_amdgcn_s_setprio(1);
#pragma unroll
      for (int mi = 0; mi < 2; ++mi)
#pragma unroll
        for (int ni = 0; ni < 4; ++ni)
          acc[mi][ni] = MFMA16(af[mi], bfr[ni], acc[mi][ni]);
      __builtin_amdgcn_s_setprio(0);
    }
    __syncthreads();
  }

  // COMBINE: per-row normalization factor, hoisted (h is block-uniform)
  float cinv[2][4];
  if (COMBINE) {
    const int h = n0 >> 6;
#pragma unroll
    for (int mi = 0; mi < 2; ++mi)
#pragma unroll
      for (int r = 0; r < 4; ++r) {
        const long row = m0 + wm + mi * 16 + hi * 4 + r;
        cinv[mi][r] = 1.0f / (mlp[row * 16 + h] + mlp[(4096L + row) * 16 + h]);
      }
  }

#pragma unroll
  for (int ni = 0; ni < 4; ++ni) {
    const int col = n0 + ni * 16 + lo;
    const float bv = bias ? bias[col] : 0.0f;
#pragma unroll
    for (int mi = 0; mi < 2; ++mi) {
      const int mrow = m0 + wm + mi * 16 + hi * 4;
#pragma unroll
      for (int r = 0; r < 4; ++r) {
        const long row = mrow + r;
        float v = (acc[mi][ni][r] + bv) * alpha;
        if (COMBINE) {
          const float o0v = (float)Op[row * 1024 + col];
          const float o1v = (float)Op[4096L * 1024 + row * 1024 + col];
          v += (o0v + o1v) * cinv[mi][r];
        }
        C[row * (long)N + col] = (OutT)v;
      }
    }
  }
}

// Fused QKV + mem-score projection, m97 128x128 structure, 4 blocks/CU,
// XCD-swizzled flat grid (832 = 8 XCD x 104; consecutive roles share B-panel).
__global__ __launch_bounds__(256, 4) void gemm_qkv(
    const bf16* __restrict__ A, const bf16* __restrict__ B,
    const float* __restrict__ bias, bf16* __restrict__ Qo,
    bf16* __restrict__ Ko, bf16* __restrict__ Vto, float* __restrict__ MSc) {
  const int K = 1024;
  __shared__ bf16 smem[2][128 * 64];   // lA | lB; reused as transpose buf
  bf16* lA = smem[0];
  bf16* lB = smem[1];
  const int lin = blockIdx.x;
  const int role = (lin & 7) * 104 + (lin >> 3);   // 832/8 = 104 per XCD
  const int m0 = (role & 31) * 128;                // m fastest within XCD
  const int n0 = (role >> 5) * 128;
  const int tid = threadIdx.x;
  const int w = tid >> 6, l = tid & 63;
  const int hi = l >> 4, lo = l & 15;
  const int wm = (w >> 1) * 64, wn = (w & 1) * 64;

  const int sr = w * 32 + (l >> 3);
  const int sc = (l & 7) * 8;
  const long aBase = (long)(m0 + sr) * K + sc;
  const long bBase = (long)(n0 + sr) * K + sc;

  f32x4 acc[4][4] = {};

  for (int k0 = 0; k0 < K; k0 += 64) {
#pragma unroll
    for (int j = 0; j < 4; ++j) {
      gl_lds16(A + aBase + (long)8 * j * K + k0, (char*)lA + (w * 32 + 8 * j) * 128);
      gl_lds16(B + bBase + (long)8 * j * K + k0, (char*)lB + (w * 32 + 8 * j) * 128);
    }
    __syncthreads();
#pragma unroll
    for (int kk = 0; kk < 2; ++kk) {
      bf16x8 af[4], bfr[4];
#pragma unroll
      for (int i = 0; i < 4; ++i) {
        af[i]  = *(const bf16x8*)((const char*)lA + (wm + i * 16 + lo) * 128 + kk * 64 + hi * 16);
        bfr[i] = *(const bf16x8*)((const char*)lB + (wn + i * 16 + lo) * 128 + kk * 64 + hi * 16);
      }
#pragma unroll
      for (int mi = 0; mi < 4; ++mi)
#pragma unroll
        for (int ni = 0; ni < 4; ++ni)
          acc[mi][ni] = MFMA16(af[mi], bfr[ni], acc[mi][ni]);
    }
    __syncthreads();
  }

  if (n0 < 2048) {       // Q or K
#pragma unroll
    for (int ni = 0; ni < 4; ++ni) {
      const int col = n0 + wn + ni * 16 + lo;
      const float bv = bias[col];
#pragma unroll
      for (int mi = 0; mi < 4; ++mi) {
        const int mrow = m0 + wm + mi * 16 + hi * 4;
#pragma unroll
        for (int r = 0; r < 4; ++r) {
          const long row = mrow + r;
          const float v = acc[mi][ni][r] + bv;
          if (n0 < 1024) Qo[row * 1024 + col] = (bf16)v;
          else           Ko[row * 1024 + (col - 1024)] = (bf16)v;
        }
      }
    }
  } else if (n0 < 3072) {  // V: transpose through LDS, coalesced Vt writes
    bf16* sT = smem[0];
#pragma unroll
    for (int ni = 0; ni < 4; ++ni) {
      const int cT = wn + ni * 16 + lo;
      const float bv = bias[n0 + cT];
#pragma unroll
      for (int mi = 0; mi < 4; ++mi) {
        const int rT = wm + mi * 16 + hi * 4;
        u32x2 pw = {cvtpk_bf16(acc[mi][ni][0] + bv, acc[mi][ni][1] + bv),
                    cvtpk_bf16(acc[mi][ni][2] + bv, acc[mi][ni][3] + bv)};
        *(u32x2*)((char*)sT + cT * 256 + ((rT * 2) ^ ((cT & 15) << 3))) = pw;
      }
    }
    __syncthreads();
    const long vrow0 = (long)(m0 >> 11) * 1024 + (n0 - 2048);
    const int srow = m0 & 2047;
#pragma unroll
    for (int dd = 0; dd < 32; ++dd) {
      const int d = w * 32 + dd;
      const unsigned pv = *(const unsigned*)((const char*)sT + d * 256 + ((l * 4) ^ ((d & 15) << 3)));
      *(unsigned*)((char*)(Vto + (vrow0 + d) * 2048 + srow) + l * 4) = pv;
    }
  } else {               // mem-scores -> MSc fp32 [4096][256]
#pragma unroll
    for (int ni = 0; ni < 4; ++ni) {
      const int col = n0 + wn + ni * 16 + lo;
      const float bv = bias[col];
      const int cm = col - 3072;
#pragma unroll
      for (int mi = 0; mi < 4; ++mi) {
        const int mrow = m0 + wm + mi * 16 + hi * 4;
#pragma unroll
        for (int r = 0; r < 4; ++r)
          MSc[(long)(mrow + r) * 256 + cm] = acc[mi][ni][r] + bv;
      }
    }
  }
}

// ---------------------------------------------------------------------------
// Flash attention, swapped-QK^T 32x32, KEY-SPLIT x2, FIXED-SHIFT softmax.
__global__ __launch_bounds__(256, 4) void attn_fwd(
    const bf16* __restrict__ Q, const bf16* __restrict__ Km,
    const bf16* __restrict__ Vt, const float* __restrict__ M2,
    bf16* __restrict__ Opart, float* __restrict__ ml) {
  __shared__ bf16 lK[2][64 * 64];
  __shared__ bf16 lV[2][64 * 64];
  __shared__ alignas(16) float lM[2][64];
  const int tid = threadIdx.x, w = tid >> 6, l = tid & 63;
  const int q31 = l & 31, h32 = l >> 5;
  const int b = blockIdx.z >> 1, half = blockIdx.z & 1;
  const int hh = blockIdx.y, q0 = blockIdx.x * 128;
  const long S = 2048, H = 1024;
  const int kbase = half * 1024;

  bf16x8 qf[4];
  const long qrow = (long)b * S + q0 + w * 32 + q31;
#pragma unroll
  for (int sl = 0; sl < 4; ++sl)
    qf[sl] = *(const bf16x8*)(Q + qrow * H + hh * 64 + sl * 16 + h32 * 8);

  f32x16 o0 = {}, o1 = {};
  float lrun = 0.0f;

  const int swr = w * 16 + (l >> 3);
  const int swc = ((l & 7) ^ (l >> 3)) * 8;

  auto stage = [&](int p, int k0) {
#pragma unroll
    for (int j = 0; j < 2; ++j) {
      gl_lds16(Km + ((long)b * S + k0 + swr + 8 * j) * H + hh * 64 + swc,
               (char*)lK[p] + (w * 16 + 8 * j) * 128);
      gl_lds16(Vt + ((long)b * H + hh * 64 + swr + 8 * j) * S + k0 + swc,
               (char*)lV[p] + (w * 16 + 8 * j) * 128);
    }
    if (w == 0) gl_lds4(M2 + (long)b * S + k0 + l, (char*)lM[p]);
  };

  stage(0, kbase);
  __syncthreads();

  for (int t = 0; t < 16; ++t) {
    const int p = t & 1;
    if (t < 15) stage(p ^ 1, kbase + (t + 1) * 64);

    // init accumulators with shifted mask; reg r -> key (r&3)+8*(r>>2)+4*h32
    f32x16 s0, s1;
#pragma unroll
    for (int g = 0; g < 4; ++g) {
      const f32x4 m0 = *(const f32x4*)&lM[p][8 * g + 4 * h32];
      const f32x4 m1 = *(const f32x4*)&lM[p][32 + 8 * g + 4 * h32];
#pragma unroll
      for (int r = 0; r < 4; ++r) {
        s0[4 * g + r] = m0[r];
        s1[4 * g + r] = m1[r];
      }
    }

    // S = K Q^T (swapped); already exp2-scaled + shifted
    __builtin_amdgcn_s_setprio(1);
#pragma unroll
    for (int sl = 0; sl < 4; ++sl) {
      const int ch = sl * 2 + h32;
      const int cx = (ch ^ (q31 & 7)) * 16;
      const bf16x8 k0f = *(const bf16x8*)((const char*)lK[p] + q31 * 128 + cx);
      const bf16x8 k1f = *(const bf16x8*)((const char*)lK[p] + (32 + q31) * 128 + cx);
      s0 = MFMA32(k0f, qf[sl], s0);
      s1 = MFMA32(k1f, qf[sl], s1);
    }
    __builtin_amdgcn_s_setprio(0);

    // P = exp2(S) directly (fixed shift already applied)
#pragma unroll
    for (int i = 0; i < 16; ++i) s0[i] = __builtin_amdgcn_exp2f(s0[i]);
#pragma unroll
    for (int i = 0; i < 16; ++i) s1[i] = __builtin_amdgcn_exp2f(s1[i]);

    // row sum: in-lane tree + one cross-half shuffle
    f32x16 ts;
#pragma unroll
    for (int i = 0; i < 16; ++i) ts[i] = s0[i] + s1[i];
#pragma unroll
    for (int i = 0; i < 8; ++i) ts[i] += ts[i + 8];
#pragma unroll
    for (int i = 0; i < 4; ++i) ts[i] += ts[i + 4];
    float rs = (ts[0] + ts[1]) + (ts[2] + ts[3]);
    rs += __shfl_xor(rs, 32, 64);
    lrun += rs;

    // P -> PV A-frags: cvt_pk + permlane32_swap (T12)
    bf16x8 pa[4];
#pragma unroll
    for (int ks = 0; ks < 4; ++ks) {
      const int rb = (ks & 1) * 8;
      unsigned a0, a1, b0, b1;
      if (ks < 2) {
        a0 = cvtpk_bf16(s0[rb + 0], s0[rb + 1]);
        a1 = cvtpk_bf16(s0[rb + 2], s0[rb + 3]);
        b0 = cvtpk_bf16(s0[rb + 4], s0[rb + 5]);
        b1 = cvtpk_bf16(s0[rb + 6], s0[rb + 7]);
      } else {
        a0 = cvtpk_bf16(s1[rb + 0], s1[rb + 1]);
        a1 = cvtpk_bf16(s1[rb + 2], s1[rb + 3]);
        b0 = cvtpk_bf16(s1[rb + 4], s1[rb + 5]);
        b1 = cvtpk_bf16(s1[rb + 6], s1[rb + 7]);
      }
      const u32x2 r02 = __builtin_amdgcn_permlane32_swap(a0, b0, false, false);
      const u32x2 r13 = __builtin_amdgcn_permlane32_swap(a1, b1, false, false);
      const u32x4 pw = {r02[0], r13[0], r02[1], r13[1]};
      pa[ks] = __builtin_bit_cast(bf16x8, pw);
    }

    // O += P V
    __builtin_amdgcn_s_setprio(1);
#pragma unroll
    for (int ks = 0; ks < 4; ++ks) {
      const int ch = ks * 2 + h32;
      const int cx = (ch ^ (q31 & 7)) * 16;
      const bf16x8 v0 = *(const bf16x8*)((const char*)lV[p] + q31 * 128 + cx);
      const bf16x8 v1 = *(const bf16x8*)((const char*)lV[p] + (32 + q31) * 128 + cx);
      o0 = MFMA32(pa[ks], v0, o0);
      o1 = MFMA32(pa[ks], v1, o1);
    }
    __builtin_amdgcn_s_setprio(0);
    __syncthreads();
  }

  // epilogue: unnormalized O + l per (q,head,half)
  if (h32 == 0)
    ml[((long)half * 4096 + (long)b * 2048 + q0 + w * 32 + q31) * 16 + hh] = lrun;
#pragma unroll
  for (int reg = 0; reg < 16; ++reg) {
    const int row = (reg & 3) + 8 * (reg >> 2) + 4 * h32;
    const long qg = (long)b * 2048 + q0 + w * 32 + row;
    Opart[((long)half * 4096 + qg) * 1024 + hh * 64 + q31]      = (bf16)o0[reg];
    Opart[((long)half * 4096 + qg) * 1024 + hh * 64 + 32 + q31] = (bf16)o1[reg];
  }
}

// ---------------------------------------------------------------------------
extern "C" void kernel_launch(void* const* d_in, const int* in_sizes, int n_in,
                              void* d_out, int out_size, void* d_ws, size_t ws_size,
                              hipStream_t stream) {
  const float* X    = (const float*)d_in[0];
  const float* mask = (const float*)d_in[1];
  const float* Wq   = (const float*)d_in[2];  const float* bq  = (const float*)d_in[3];
  const float* Wk   = (const float*)d_in[4];  const float* bk  = (const float*)d_in[5];
  const float* Wv   = (const float*)d_in[6];  const float* bv  = (const float*)d_in[7];
  const float* Wo   = (const float*)d_in[8];  const float* bo  = (const float*)d_in[9];
  const float* mv   = (const float*)d_in[10];
  const float* Wmp  = (const float*)d_in[11]; const float* bmp = (const float*)d_in[12];
  const float* Wma  = (const float*)d_in[13]; const float* bma = (const float*)d_in[14];

  char* ws = (char*)d_ws;
  size_t off = 0;
  auto alloc = [&](size_t bytes) -> void* {
    void* p = ws + off;
    off += (bytes + 255) & ~(size_t)255;
    return p;
  };
  const long MS_ = 4096;
  bf16* Xb    = (bf16*)alloc(MS_ * 1024 * 2);
  bf16* Wqkvb = (bf16*)alloc(3328L * 1024 * 2);   // [Wq*QS | Wk | Wv | Wma]
  bf16* Wob   = (bf16*)alloc(1024 * 1024 * 2);
  bf16* Wmpb  = (bf16*)alloc(1024 * 512 * 2);
  bf16* mvb   = (bf16*)alloc(256 * 512 * 2);
  bf16* WfoldT= (bf16*)alloc(1024 * 256 * 2);     // Wmp @ mv^T
  float* M2   = (float*)alloc(MS_ * 4);
  float* bqkv = (float*)alloc(3328 * 4);
  bf16* Qb    = (bf16*)alloc(MS_ * 1024 * 2);
  bf16* Kb    = (bf16*)alloc(MS_ * 1024 * 2);
  bf16* Vtb   = (bf16*)alloc(MS_ * 1024 * 2);     // [B][h*64+d][S]
  bf16* Opart = (bf16*)alloc(2 * MS_ * 1024 * 2); // [2][4096][1024] = 16MB
  float* ml   = (float*)alloc(2 * MS_ * 16 * 4);  // [2][4096][16]
  float* MSc  = (float*)alloc(MS_ * 256 * 4);
  bf16* MP    = (bf16*)alloc(MS_ * 256 * 2);
  bf16* CB    = Qb;                               // dead after attn

  // 1: prep
  fused_prep<<<9096, 256, 0, stream>>>(X, Wq, Wk, Wv, Wo, Wma, Wmp, mask,
                                       bq, bk, bv, bma, mv,
                                       Xb, Wqkvb, Wob, Wmpb, M2, bqkv, mvb);
  // 2: WfoldT = Wmp @ mv^T  [1024][256]  (folds memory_values into Wmp)
  gemm_bt<bf16, false><<<dim3(4, 8), 256, 0, stream>>>(Wmpb, mvb, nullptr, nullptr, nullptr,
                                                       WfoldT, 1024, 256, 512, 1.0f);
  // 3: fused QKV + mem-score projection (XCD-swizzled flat grid, 4 blocks/CU)
  gemm_qkv<<<832, 256, 0, stream>>>(Xb, Wqkvb, bqkv, Qb, Kb, Vtb, MSc);
  // 4: attention, key-split x2 (combine deferred into gemm #6)
  attn_fwd<<<dim3(16, 16, 4), 256, 0, stream>>>(Qb, Kb, Vtb, M2, Opart, ml);
  // 5: mem-path softmax
  softmax_rows256<<<1024, 256, 0, stream>>>(MSc, MP);
  // 6: combined = 0.3*(probs @ WfoldT^T + bmp) + combine(Opart, ml)
  //    (identity: probs@(Wmp@mv^T)^T = (probs@mv)@Wmp^T)
  gemm_bt<bf16, true><<<dim3(16, 32), 256, 0, stream>>>(MP, WfoldT, bmp, Opart, ml,
                                                        CB, 4096, 1024, 256, 0.3f);
  // 7: final projection -> fp32 out
  gemm_bt<float, false><<<dim3(16, 32), 256, 0, stream>>>(CB, Wob, bo, nullptr, nullptr,
                                                          (float*)d_out, 4096, 1024, 1024, 1.0f);
}